// Round 3
// baseline (393.894 us; speedup 1.0000x reference)
//
#include <hip/hip_runtime.h>
#include <stdint.h>

typedef unsigned short u16;
typedef __attribute__((ext_vector_type(8))) short short8;
typedef __attribute__((ext_vector_type(4))) short short4_t;
typedef __attribute__((ext_vector_type(4))) float f32x4;

__device__ __forceinline__ float b2f(u16 u){ union{unsigned i; float f;}v; v.i=((unsigned)u)<<16; return v.f; }
__device__ __forceinline__ u16 f2b(float f){ unsigned x=__float_as_uint(f); return (u16)((x + 0x7fffu + ((x>>16)&1u))>>16); }

#if __has_builtin(__builtin_amdgcn_exp2f)
#define EXP2F(x) __builtin_amdgcn_exp2f(x)
#else
#define EXP2F(x) exp2f(x)
#endif

#if __has_builtin(__builtin_amdgcn_mfma_f32_16x16x16_bf16)
#define MFMA16(a,b,c) __builtin_amdgcn_mfma_f32_16x16x16_bf16(a,b,c,0,0,0)
#elif __has_builtin(__builtin_amdgcn_mfma_f32_16x16x16bf16_1k)
#define MFMA16(a,b,c) __builtin_amdgcn_mfma_f32_16x16x16bf16_1k(a,b,c,0,0,0)
#else
static __device__ __forceinline__ f32x4 mfma16_asm(short4_t a, short4_t b, f32x4 c){
  __asm__("v_mfma_f32_16x16x16_bf16 %0, %1, %2, %3" : "=v"(c) : "v"(a), "v"(b), "0"(c));
  return c;
}
#define MFMA16(a,b,c) mfma16_asm(a,b,c)
#endif

__device__ __forceinline__ void async16(const void* g, void* l){
  __builtin_amdgcn_global_load_lds((const __attribute__((address_space(1))) void*)g,
                                   (__attribute__((address_space(3))) void*)l, 16, 0, 0);
}

// pack 4 fp32 (in [0,1]) -> 4 bf16 (round-half-up) as K=16 A-fragment regs
__device__ __forceinline__ short4_t pack4(f32x4 s){
  unsigned u0 = (__float_as_uint(s[0]) + 0x8000u) >> 16;
  unsigned u1 = (__float_as_uint(s[1]) + 0x8000u) & 0xffff0000u;
  unsigned u2 = (__float_as_uint(s[2]) + 0x8000u) >> 16;
  unsigned u3 = (__float_as_uint(s[3]) + 0x8000u) & 0xffff0000u;
  union { unsigned v[2]; short4_t s4; } r;
  r.v[0] = u0 | u1; r.v[1] = u2 | u3;
  return r.s4;
}

// ---------------- LayerNorm (E=1024, one block per row) ----------------
template<int IN_F32>
__global__ __launch_bounds__(256) void ln_kernel(const void* __restrict__ xin,
    const float* __restrict__ g, const float* __restrict__ b, u16* __restrict__ y)
{
  const int E = 1024;
  int row = blockIdx.x, t = threadIdx.x;
  float f0,f1,f2,f3;
  if (IN_F32){
    const float* xr = (const float*)xin + (size_t)row*E;
    float4 xv = *(const float4*)(xr + t*4);
    f0=xv.x; f1=xv.y; f2=xv.z; f3=xv.w;
  } else {
    const u16* xr = (const u16*)xin + (size_t)row*E;
    ushort4 xv = *(const ushort4*)(xr + t*4);
    f0=b2f(xv.x); f1=b2f(xv.y); f2=b2f(xv.z); f3=b2f(xv.w);
  }
  float s1 = f0+f1+f2+f3;
  float s2 = f0*f0+f1*f1+f2*f2+f3*f3;
  #pragma unroll
  for (int off=32; off>=1; off>>=1){ s1 += __shfl_xor(s1,off); s2 += __shfl_xor(s2,off); }
  __shared__ float red[8];
  int w = t>>6;
  if ((t&63)==0){ red[w]=s1; red[4+w]=s2; }
  __syncthreads();
  float S1 = red[0]+red[1]+red[2]+red[3];
  float S2 = red[4]+red[5]+red[6]+red[7];
  float mean = S1*(1.0f/E);
  float var  = S2*(1.0f/E) - mean*mean;
  float inv  = rsqrtf(var + 1e-5f);
  float4 gv = *(const float4*)(g + t*4);
  float4 bv = *(const float4*)(b + t*4);
  ushort4 o;
  o.x = f2b((f0-mean)*inv*gv.x+bv.x);
  o.y = f2b((f1-mean)*inv*gv.y+bv.y);
  o.z = f2b((f2-mean)*inv*gv.z+bv.z);
  o.w = f2b((f3-mean)*inv*gv.w+bv.w);
  *(ushort4*)(y + (size_t)row*E + t*4) = o;
}

// ---------------- out = bias + residual (fp32 out, bf16 residual) ----------------
__global__ __launch_bounds__(256) void resbias_f32(float* __restrict__ out, const float* __restrict__ bias,
                                                   const u16* __restrict__ res)
{
  int idx = blockIdx.x*256 + threadIdx.x;       // one float4 per thread
  int col4 = (idx & 255)*4;                      // 1024 cols = 256 float4
  ushort4 r = *(const ushort4*)(res + (size_t)idx*4);
  float4 bv = *(const float4*)(bias + col4);
  float4 o;
  o.x = bv.x + b2f(r.x);
  o.y = bv.y + b2f(r.y);
  o.z = bv.z + b2f(r.z);
  o.w = bv.w + b2f(r.w);
  *(float4*)(out + (size_t)idx*4) = o;
}

// ---------------- fp32->bf16 64x64-tiled transpose ----------------
__global__ __launch_bounds__(256) void transpose_bt(const float* __restrict__ src, u16* __restrict__ dst,
                                                    int ld_src, int ld_dst)
{
  __shared__ u16 tile[64*66];
  int c0 = blockIdx.x*64, r0 = blockIdx.y*64;
  int t = threadIdx.x;
  #pragma unroll
  for (int i=0;i<16;++i){
    int lin = i*256 + t;
    int rr = lin>>6, cc = lin&63;
    tile[cc*66+rr] = f2b(src[(size_t)(r0+rr)*ld_src + c0+cc]);
  }
  __syncthreads();
  #pragma unroll
  for (int i=0;i<16;++i){
    int lin = i*256 + t;
    int cc = lin>>6, rr = lin&63;
    dst[(size_t)(c0+cc)*ld_dst + r0+rr] = tile[cc*66+rr];
  }
}

// ---------------- QKV weight repack ----------------
__global__ __launch_bounds__(256) void qkv_repack(const float* __restrict__ wq, const float* __restrict__ wk,
                                                  const float* __restrict__ wv, u16* __restrict__ dst)
{
  __shared__ u16 tile[64*66];
  int e0 = blockIdx.x*64;
  int sel = blockIdx.y>>4, h = blockIdx.y&15;
  const float* src = (sel==0?wq:(sel==1?wk:wv)) + (size_t)h*1024*64;
  int t = threadIdx.x;
  #pragma unroll
  for (int i=0;i<16;++i){
    int lin=i*256+t; int rr=lin>>6, cc=lin&63;
    tile[cc*66+rr] = f2b(src[(size_t)(e0+rr)*64 + cc]);
  }
  __syncthreads();
  #pragma unroll
  for (int i=0;i<16;++i){
    int lin=i*256+t; int cc=lin>>6, rr=lin&63;
    dst[(size_t)(sel*1024 + h*64 + cc)*1024 + e0+rr] = tile[cc*66+rr];
  }
}

// ---------------- V transpose: qkv V-slice -> VT[bh][64][2048] ----------------
__global__ __launch_bounds__(256) void vtrans(const u16* __restrict__ qkv, u16* __restrict__ VT)
{
  __shared__ u16 tile[64*66];
  int bh = blockIdx.y, bb = bh>>4, h = bh&15;
  int s0 = blockIdx.x*64;
  const u16* src = qkv + ((size_t)(bb*2048) + s0)*3072 + 2048 + h*64;
  int t = threadIdx.x;
  int sr = t>>3, c0 = (t&7)*8;
  #pragma unroll
  for (int half=0; half<2; ++half){
    const u16* p = src + (size_t)(sr+half*32)*3072 + c0;
    ushort4 v0 = *(const ushort4*)p;
    ushort4 v1 = *(const ushort4*)(p+4);
    uint* d = (uint*)(tile + (sr+half*32)*66 + c0);
    d[0] = (uint)v0.x | ((uint)v0.y<<16);
    d[1] = (uint)v0.z | ((uint)v0.w<<16);
    d[2] = (uint)v1.x | ((uint)v1.y<<16);
    d[3] = (uint)v1.z | ((uint)v1.w<<16);
  }
  __syncthreads();
  u16* out = VT + (size_t)bh*64*2048 + s0;
  int dw = t>>3, sc = (t&7)*8;
  #pragma unroll
  for (int half=0; half<2; ++half){
    int d = dw + half*32;
    short8 pk;
    #pragma unroll
    for (int j=0;j<8;++j) pk[j] = (short)tile[(sc+j)*66 + d];
    *(short8*)(out + (size_t)d*2048 + sc) = pk;
  }
}

// ---------------- bf16 GEMM: C[M][N] = A[M][K] * Bt[N][K]^T (legacy 2-phase) ----------------
template<int MI>
__global__ __launch_bounds__(256, 3) void gemm_bt(const u16* __restrict__ A, const u16* __restrict__ Bt,
    u16* __restrict__ C, float* __restrict__ Cf, int M, int N, int K,
    const float* __restrict__ bias, const u16* __restrict__ residual, int do_relu, int gx)
{
  __shared__ __align__(16) u16 As[2][MI*32*64];
  __shared__ __align__(16) u16 Bs[2][128*64];
  int t = threadIdx.x;
  int bid = blockIdx.y * gridDim.x + blockIdx.x;
  int xcd = bid & 7, slot = bid >> 3;
  int gy = 8 / gx;
  int rx = gridDim.x / gx, ry = gridDim.y / gy;
  int col_b = (xcd % gx) * rx + (slot % rx);
  int row_b = (xcd / gx) * ry + (slot / rx);
  int row0 = row_b*(MI*32), col0 = col_b*128;
  int l = t&63, w = t>>6;
  int wm = (w>>1)*(MI*16), wn = (w&1)*64;
  int lr = l&15, lq = l>>4;
  (void)M;

  f32x4 acc[MI][4];
  #pragma unroll
  for (int i=0;i<MI;++i)
    #pragma unroll
    for (int j=0;j<4;++j) acc[i][j] = f32x4{0.f,0.f,0.f,0.f};

  const u16* gA = A  + (size_t)(row0 + (t>>3))*K + (((t&7)^((t>>3)&7))<<3);
  const u16* gB = Bt + (size_t)(col0 + (t>>3))*K + (((t&7)^((t>>3)&7))<<3);
  const size_t rnd = (size_t)32*K;
  int nk = K>>6;

  #pragma unroll
  for (int r=0;r<MI;++r) async16(gA + r*rnd, As[0] + r*2048 + t*8);
  #pragma unroll
  for (int r=0;r<4;++r)  async16(gB + r*rnd, Bs[0] + r*2048 + t*8);

  int sw8 = (lr&7);
  for (int kt=0; kt<nk; ++kt){
    int cur = kt&1;
    __syncthreads();
    if (kt+1 < nk){
      int ko = (kt+1)<<6;
      #pragma unroll
      for (int r=0;r<MI;++r) async16(gA + r*rnd + ko, As[cur^1] + r*2048 + t*8);
      #pragma unroll
      for (int r=0;r<4;++r)  async16(gB + r*rnd + ko, Bs[cur^1] + r*2048 + t*8);
    }
    const u16* as = As[cur];
    const u16* bs = Bs[cur];
    #pragma unroll
    for (int kk=0;kk<2;++kk){
      int so = (((kk*4+lq)^sw8))<<3;
      short8 a[MI], b[4];
      #pragma unroll
      for (int i=0;i<MI;++i) a[i] = *(const short8*)(as + (wm+i*16+lr)*64 + so);
      #pragma unroll
      for (int j=0;j<4;++j)  b[j] = *(const short8*)(bs + (wn+j*16+lr)*64 + so);
      #pragma unroll
      for (int i=0;i<MI;++i)
        #pragma unroll
        for (int j=0;j<4;++j)
          acc[i][j] = __builtin_amdgcn_mfma_f32_16x16x32_bf16(a[i], b[j], acc[i][j], 0,0,0);
    }
  }

  #pragma unroll
  for (int i=0;i<MI;++i){
    #pragma unroll
    for (int j=0;j<4;++j){
      int col = col0 + wn + j*16 + lr;
      float bv = bias ? bias[col] : 0.0f;
      #pragma unroll
      for (int r=0;r<4;++r){
        int row = row0 + wm + i*16 + lq*4 + r;
        float v = acc[i][j][r] + bv;
        if (do_relu) v = fmaxf(v, 0.0f);
        if (residual) v += b2f(residual[(size_t)row*N + col]);
        if (Cf) Cf[(size_t)row*N + col] = v;
        else    C [(size_t)row*N + col] = f2b(v);
      }
    }
  }
}

// ---------------- bf16 GEMM 256x256 tile, 8 waves, 4-phase/K-tile, counted vmcnt ----------------
// Per K-tile (BK=64): 4 phases = C-quadrants in snake order (0,0),(0,1),(1,1),(1,0).
// A-tile LDS phys layout: phys = qm*128 + wr*64 + (mm*16+lr)  -> group A0=phys[0,128), A1=[128,256)
// B-tile LDS phys layout: phys = qn*128 + wc*32 + (nn*16+lr)  -> group B0, B1
// Staging for tile kt+1 issued in need-order A0,B0,B1,A1 (2 global_load_lds per phase);
// waits: vmcnt(4) end of phases 0,1,3 (none at 2) -> never drains to 0 in the main loop.
// LDS rows swizzled chunk^(row&7) via pre-swizzled global source (both-sides rule).
// Split-K (gridDim.z>1): each z-chunk covers K columns starting at z*K (row stride ldk);
// partials accumulated with fp32 global atomics into Cf (pre-initialized with bias+residual).
__global__ __launch_bounds__(512,2) void gemm256(const u16* __restrict__ A, const u16* __restrict__ Bt,
    u16* __restrict__ C, float* __restrict__ Cf, int N, int K, int ldk,
    const float* __restrict__ bias, const u16* __restrict__ residual, int do_relu, int gx, int atomic)
{
  __shared__ __align__(16) u16 As[2][256*64];
  __shared__ __align__(16) u16 Bs[2][256*64];
  int t = threadIdx.x;
  int bid = (blockIdx.z*gridDim.y + blockIdx.y)*gridDim.x + blockIdx.x;
  int xcd = bid & 7, slot = bid >> 3;
  int npc8 = (gridDim.x*gridDim.y) >> 3;   // slots per chunk per xcd
  int s = slot % npc8;
  int gy = 8/gx;
  int rx = gridDim.x/gx, ry = gridDim.y/gy;
  int col_b = (xcd%gx)*rx + s%rx;
  int row_b = (xcd/gx)*ry + s/rx;
  int row0 = row_b*256, col0 = col_b*256;
  int l = t&63, w = t>>6;
  int wr = w>>2, wc = w&3;           // 2 x 4 wave grid, per-wave 128(M) x 64(N)
  int lr = l&15, lq = l>>4, sw = lr&7;

  f32x4 acc[8][4];
  #pragma unroll
  for (int m=0;m<8;++m)
    #pragma unroll
    for (int n=0;n<4;++n) acc[m][n] = f32x4{0.f,0.f,0.f,0.f};

  // staging addressing: thread covers phys row ss*64 + (t>>3), chunk (t&7); source pre-swizzled
  int i = t>>3, c8 = t&7;
  int swc = (c8 ^ (i&7))*8;
  const u16* Ab = A  + (size_t)blockIdx.z*K;
  const u16* Bb = Bt + (size_t)blockIdx.z*K;
  const u16* aS[4]; const u16* bS[4];
  {
    int la[4] = { i, 128+i, 64+i, 192+i };   // phys->logical for A sites 0..3
    #pragma unroll
    for (int ss=0;ss<4;++ss){
      aS[ss] = Ab + (size_t)(row0 + la[ss])*ldk + swc;
      int p = ss*64 + i;
      int lb = ((p>>5)&3)*64 + (p>>7)*32 + (p&31);  // phys->logical for B
      bS[ss] = Bb + (size_t)(col0 + lb)*ldk + swc;
    }
  }
  int nk = K>>6;

  // prologue: stage tile 0 in wait-group order A0,B0,B1,A1
  async16(aS[0], As[0] + 0*4096 + t*8);
  async16(aS[1], As[0] + 1*4096 + t*8);
  async16(bS[0], Bs[0] + 0*4096 + t*8);
  async16(bS[1], Bs[0] + 1*4096 + t*8);
  async16(bS[2], Bs[0] + 2*4096 + t*8);
  async16(bS[3], Bs[0] + 3*4096 + t*8);
  async16(aS[2], As[0] + 2*4096 + t*8);
  async16(aS[3], As[0] + 3*4096 + t*8);
  asm volatile("s_waitcnt vmcnt(4)" ::: "memory");   // A0,B0 of tile 0 landed; B1,A1 in flight
  __builtin_amdgcn_s_barrier();

  short8 af[4][2], bf[2][2];

#define RD_A(qm) \
  _Pragma("unroll") \
  for (int mm=0;mm<4;++mm){ \
    _Pragma("unroll") \
    for (int kk=0;kk<2;++kk) \
      af[mm][kk] = *(const short8*)(asC + ((qm)*128 + wr*64 + mm*16 + lr)*64 + (((kk*4+lq)^sw)<<3)); \
  }
#define RD_B(qn) \
  _Pragma("unroll") \
  for (int nn=0;nn<2;++nn){ \
    _Pragma("unroll") \
    for (int kk=0;kk<2;++kk) \
      bf[nn][kk] = *(const short8*)(bsC + ((qn)*128 + wc*32 + nn*16 + lr)*64 + (((kk*4+lq)^sw)<<3)); \
  }
#define MMQ(qm,qn) \
  __builtin_amdgcn_s_setprio(1); \
  _Pragma("unroll") \
  for (int mm=0;mm<4;++mm){ \
    _Pragma("unroll") \
    for (int nn=0;nn<2;++nn){ \
      _Pragma("unroll") \
      for (int kk=0;kk<2;++kk) \
        acc[(qm)*4+mm][(qn)*2+nn] = __builtin_amdgcn_mfma_f32_16x16x32_bf16(af[mm][kk], bf[nn][kk], acc[(qm)*4+mm][(qn)*2+nn], 0,0,0); \
    } \
  } \
  __builtin_amdgcn_s_setprio(0);
#define BARW \
  __builtin_amdgcn_s_barrier(); \
  asm volatile("s_waitcnt lgkmcnt(0)" ::: "memory"); \
  __builtin_amdgcn_sched_barrier(0);
#define PIN __builtin_amdgcn_sched_barrier(0);

  for (int kt=0; kt<nk-1; ++kt){
    int cur = kt&1;
    const u16* asC = As[cur]; const u16* bsC = Bs[cur];
    u16* asN = As[cur^1];    u16* bsN = Bs[cur^1];
    int ko = (kt+1)<<6;
    // phase 0: quadrant (0,0); stage A0'
    RD_A(0); RD_B(0);
    async16(aS[0]+ko, asN + 0*4096 + t*8);
    async16(aS[1]+ko, asN + 1*4096 + t*8);
    PIN;
    asm volatile("s_waitcnt vmcnt(4)" ::: "memory");  // drains B1_cur (needed ph1)
    BARW;
    MMQ(0,0);
    __builtin_amdgcn_s_barrier();
    // phase 1: quadrant (0,1), reuse af; stage B0'
    RD_B(1);
    async16(bS[0]+ko, bsN + 0*4096 + t*8);
    async16(bS[1]+ko, bsN + 1*4096 + t*8);
    PIN;
    asm volatile("s_waitcnt vmcnt(4)" ::: "memory");  // drains A1_cur (needed ph2)
    BARW;
    MMQ(0,1);
    __builtin_amdgcn_s_barrier();
    // phase 2: quadrant (1,1), reuse bf; stage B1' (no wait needed)
    RD_A(1);
    async16(bS[2]+ko, bsN + 2*4096 + t*8);
    async16(bS[3]+ko, bsN + 3*4096 + t*8);
    PIN;
    BARW;
    MMQ(1,1);
    __builtin_amdgcn_s_barrier();
    // phase 3: quadrant (1,0), reuse af; stage A1'
    RD_B(0);
    async16(aS[2]+ko, asN + 2*4096 + t*8);
    async16(aS[3]+ko, asN + 3*4096 + t*8);
    PIN;
    asm volatile("s_waitcnt vmcnt(4)" ::: "memory");  // drains A0',B0' (needed next ph0)
    BARW;
    MMQ(1,0);
    __builtin_amdgcn_s_barrier();
  }
  { // last tile: no staging, conservative drains
    int cur = (nk-1)&1;
    const u16* asC = As[cur]; const u16* bsC = Bs[cur];
    RD_A(0); RD_B(0);
    asm volatile("s_waitcnt vmcnt(2)" ::: "memory");  // drain B1_last
    BARW;
    MMQ(0,0);
    __builtin_amdgcn_s_barrier();
    RD_B(1);
    asm volatile("s_waitcnt vmcnt(0)" ::: "memory");  // drain A1_last
    BARW;
    MMQ(0,1);
    __builtin_amdgcn_s_barrier();
    RD_A(1);
    BARW;
    MMQ(1,1);
    __builtin_amdgcn_s_barrier();
    RD_B(0);
    BARW;
    MMQ(1,0);
  }
#undef RD_A
#undef RD_B
#undef MMQ
#undef BARW
#undef PIN

  #pragma unroll
  for (int m=0;m<8;++m){
    #pragma unroll
    for (int n=0;n<4;++n){
      int col = col0 + wc*64 + n*16 + lr;
      float bv = bias ? bias[col] : 0.0f;
      #pragma unroll
      for (int r=0;r<4;++r){
        int row = row0 + wr*128 + m*16 + lq*4 + r;
        float v = acc[m][n][r] + bv;
        if (do_relu) v = fmaxf(v, 0.0f);
        if (residual) v += b2f(residual[(size_t)row*N + col]);
        if (atomic)     atomicAdd(&Cf[(size_t)row*N + col], v);
        else if (Cf)    Cf[(size_t)row*N + col] = v;
        else            C [(size_t)row*N + col] = f2b(v);
      }
    }
  }
}

// ---------------- causal flash attention v4 ----------------
// Q-tile 64 (4 waves x 16 q rows), s-tile 64 double-buffered, grid 1024.
// S^T via K=32 mfma; P stays IN-LANE (C-layout == K=16 A-layout), PV via
// 16x16x16 mfma on packed bf16 — no P LDS round-trip. Complementary-qt
// slot pairing balances per-CU work. K and V^T staged via global_load_lds.
__global__ __launch_bounds__(256,4) void attn_kernel(const u16* __restrict__ QKV,
    const u16* __restrict__ VT, u16* __restrict__ O)
{
  const int T=2048, LD=3072, E=1024;
  int bid = blockIdx.y * gridDim.x + blockIdx.x;
  int xcd = bid & 7, slot = bid >> 3;
  int idx = slot & 31, grp = slot >> 5;
  int qt = (grp & 1) ? idx : 31 - idx;   // heavy-first, complementary pairing
  int bh = xcd*4 + grp;
  int bb = bh>>4, h = bh&15;
  const u16* base = QKV + (size_t)bb*T*LD;
  const u16* Qp = base + h*64;
  const u16* Kp = base + 1024 + h*64;
  const u16* Vtp = VT + (size_t)bh*64*2048;
  int t = threadIdx.x, l = t&63, w = t>>6;
  int lr = l&15, lq = l>>4;

  __shared__ __align__(16) u16 Ks[2][64*64];   // [s][d], chunk c at slot c^(s&7)
  __shared__ __align__(16) u16 Vs[2][64*64];   // [d][s], chunk c at slot c^(d&7)

  const float QSC = 0.125f*1.44269504f;
  int q0 = qt*64 + w*16;
  short8 aq[2];
  #pragma unroll
  for (int kk=0;kk<2;++kk){
    short8 raw = *(const short8*)(Qp + (size_t)(q0+lr)*LD + kk*32 + lq*8);
    short8 sc;
    #pragma unroll
    for (int j=0;j<8;++j) sc[j] = (short)f2b(b2f((u16)raw[j])*QSC);
    aq[kk]=sc;
  }

  float mrun = -3e38f, lrun = 0.f;
  f32x4 Oacc[4];
  #pragma unroll
  for (int dt=0;dt<4;++dt) Oacc[dt] = f32x4{0.f,0.f,0.f,0.f};

  int kc = (l&7) ^ (l>>3);
  int ra = 8*w + (l>>3);

  // prologue: stage tile 0
  async16(Kp  + (size_t)ra*LD        + kc*8, Ks[0] + t*8);
  async16(Kp  + (size_t)(ra+32)*LD   + kc*8, Ks[0] + 2048 + t*8);
  async16(Vtp + (size_t)ra*2048      + kc*8, Vs[0] + t*8);
  async16(Vtp + (size_t)(ra+32)*2048 + kc*8, Vs[0] + 2048 + t*8);

  for (int it=0; it<=qt; ++it){
    int s0 = it*64, cur = it&1;
    __syncthreads();
    if (it < qt){
      int sn = s0+64;
      u16* kd = Ks[cur^1]; u16* vd = Vs[cur^1];
      async16(Kp  + (size_t)(sn+ra)*LD        + kc*8, kd + t*8);
      async16(Kp  + (size_t)(sn+ra+32)*LD     + kc*8, kd + 2048 + t*8);
      async16(Vtp + (size_t)ra*2048      + sn + kc*8, vd + t*8);
      async16(Vtp + (size_t)(ra+32)*2048 + sn + kc*8, vd + 2048 + t*8);
    }
    const u16* ks = Ks[cur];
    const u16* vs = Vs[cur];

    // S^T[s][q] for this wave's 16 q
    f32x4 S[4];
    #pragma unroll
    for (int st=0; st<4; ++st){
      short8 kf0 = *(const short8*)(ks + (st*16+lr)*64 + ((lq  )^(lr&7))*8);
      short8 kf1 = *(const short8*)(ks + (st*16+lr)*64 + ((4+lq)^(lr&7))*8);
      f32x4 z = f32x4{0.f,0.f,0.f,0.f};
      z = __builtin_amdgcn_mfma_f32_16x16x32_bf16(kf0, aq[0], z, 0,0,0);
      z = __builtin_amdgcn_mfma_f32_16x16x32_bf16(kf1, aq[1], z, 0,0,0);
      S[st] = z;
    }
    if (it == qt){
      int qg = q0 + lr;
      #pragma unroll
      for (int st=0;st<4;++st)
        #pragma unroll
        for (int r=0;r<4;++r){
          int sg = s0 + st*16 + lq*4 + r;
          if (sg > qg) S[st][r] = -3e38f;
        }
    }
    // online softmax (q = lr; s-reduction in-lane + 2 shuffles)
    float m = S[0][0];
    #pragma unroll
    for (int st=0;st<4;++st)
      #pragma unroll
      for (int r=0;r<4;++r) m = fmaxf(m, S[st][r]);
    m = fmaxf(m, __shfl_xor(m,16));
    m = fmaxf(m, __shfl_xor(m,32));
    float mnew = fmaxf(mrun, m);
    float alpha = EXP2F(mrun - mnew);
    mrun = mnew;
    float ssum = 0.f;
    #pragma unroll
    for (int st=0;st<4;++st)
      #pragma unroll
      for (int r=0;r<4;++r){ float p = EXP2F(S[st][r]-mnew); S[st][r]=p; ssum+=p; }
    ssum += __shfl_xor(ssum,16);
    ssum += __shfl_xor(ssum,32);
    lrun = lrun*alpha + ssum;
    // P: in-lane pack to K=16 A-fragments
    short4_t pk[4];
    #pragma unroll
    for (int st=0;st<4;++st) pk[st] = pack4(S[st]);
    // rescale O (O rows: q = lq*4+r)
    float af[4];
    #pragma unroll
    for (int r=0;r<4;++r) af[r] = __shfl(alpha, lq*4+r);
    #pragma unroll
    for (int dt=0;dt<4;++dt)
      #pragma unroll
      for (int r=0;r<4;++r) Oacc[dt][r] *= af[r];
    // PV: 16 x mfma_16x16x16
    #pragma unroll
    for (int st=0;st<4;++st){
      #pragma unroll
      for (int dt=0;dt<4;++dt){
        short4_t vf = *(const short4_t*)(vs + (dt*16+lr)*64 + ((2*st+(lq>>1))^(lr&7))*8 + (lq&1)*4);
        Oacc[dt] = MFMA16(pk[st], vf, Oacc[dt]);
      }
    }
  }
  float linv[4];
  #pragma unroll
  for (int r=0;r<4;++r) linv[r] = 1.0f/__shfl(lrun, lq*4+r);
  #pragma unroll
  for (int dt=0;dt<4;++dt)
    #pragma unroll
    for (int r=0;r<4;++r){
      int qg = q0 + lq*4 + r;
      O[(size_t)(bb*T+qg)*E + h*64 + dt*16 + lr] = f2b(Oacc[dt][r]*linv[r]);
    }
}

// ---------------- host ----------------
extern "C" void kernel_launch(void* const* d_in, const int* in_sizes, int n_in,
                              void* d_out, int out_size, void* d_ws, size_t ws_size,
                              hipStream_t stream)
{
  (void)in_sizes; (void)n_in; (void)out_size; (void)ws_size;
  const float* x     = (const float*)d_in[0];
  const float* wq    = (const float*)d_in[1];
  const float* wk    = (const float*)d_in[2];
  const float* wv    = (const float*)d_in[3];
  const float* wproj = (const float*)d_in[4];
  const float* bproj = (const float*)d_in[5];
  const float* g1    = (const float*)d_in[6];
  const float* be1   = (const float*)d_in[7];
  const float* g2    = (const float*)d_in[8];
  const float* be2   = (const float*)d_in[9];
  const float* w1    = (const float*)d_in[10];
  const float* b1    = (const float*)d_in[11];
  const float* w2    = (const float*)d_in[12];
  const float* b2    = (const float*)d_in[13];
  float* out = (float*)d_out;

  char* ws = (char*)d_ws;
  size_t off = 0;
  auto alloc = [&](size_t bytes)->void*{ void* p = ws + off; off += (bytes + 255) & ~(size_t)255; return p; };
  u16* hnorm  = (u16*)alloc((size_t)4096*1024*2);
  u16* qkv    = (u16*)alloc((size_t)4096*3072*2);
  u16* VT     = (u16*)alloc((size_t)32*64*2048*2);
  u16* attnO  = (u16*)alloc((size_t)4096*1024*2);
  u16* x2     = (u16*)alloc((size_t)4096*1024*2);
  u16* h2     = (u16*)alloc((size_t)4096*1024*2);
  u16* ffn1   = (u16*)alloc((size_t)4096*4096*2);
  u16* wqkvT  = (u16*)alloc((size_t)3072*1024*2);
  u16* wprojT = (u16*)alloc((size_t)1024*1024*2);
  u16* w1T    = (u16*)alloc((size_t)4096*1024*2);
  u16* w2T    = (u16*)alloc((size_t)1024*4096*2);

  qkv_repack  <<<dim3(16,48),256,0,stream>>>(wq,wk,wv,wqkvT);
  transpose_bt<<<dim3(16,16),256,0,stream>>>(wproj, wprojT, 1024, 1024);
  transpose_bt<<<dim3(64,16),256,0,stream>>>(w1,    w1T,    4096, 1024);
  transpose_bt<<<dim3(16,64),256,0,stream>>>(w2,    w2T,    1024, 4096);

  ln_kernel<1><<<4096,256,0,stream>>>(x, g1, be1, hnorm);
  gemm256<<<dim3(12,16),512,0,stream>>>(hnorm, wqkvT, qkv, nullptr, 3072, 1024, 1024, nullptr, nullptr, 0, 4, 0);
  vtrans<<<dim3(32,32),256,0,stream>>>(qkv, VT);
  attn_kernel<<<dim3(32,32),256,0,stream>>>(qkv, VT, attnO);
  gemm_bt<2><<<dim3(8,64),256,0,stream>>>(attnO, wprojT, x2, nullptr, 4096,1024,1024, bproj, hnorm, 0, 2);
  ln_kernel<0><<<4096,256,0,stream>>>(x2, g2, be2, h2);
  gemm256<<<dim3(16,16),512,0,stream>>>(h2, w1T, ffn1, nullptr, 4096, 1024, 1024, b1, nullptr, 1, 4, 0);
  // FFN2: out = b2 + h2 (init) then split-K4 gemm256 accumulating via fp32 atomics
  resbias_f32<<<4096,256,0,stream>>>(out, b2, h2);
  gemm256<<<dim3(4,16,4),512,0,stream>>>(ffn1, w2T, nullptr, out, 1024, 1024, 4096, nullptr, nullptr, 0, 2, 1);
}

// Round 6
// 366.164 us; speedup vs baseline: 1.0757x; 1.0757x over previous
//
#include <hip/hip_runtime.h>
#include <stdint.h>

typedef unsigned short u16;
typedef __attribute__((ext_vector_type(8))) short short8;
typedef __attribute__((ext_vector_type(4))) short short4_t;
typedef __attribute__((ext_vector_type(4))) float f32x4;

__device__ __forceinline__ float b2f(u16 u){ union{unsigned i; float f;}v; v.i=((unsigned)u)<<16; return v.f; }
__device__ __forceinline__ u16 f2b(float f){ unsigned x=__float_as_uint(f); return (u16)((x + 0x7fffu + ((x>>16)&1u))>>16); }

#if __has_builtin(__builtin_amdgcn_exp2f)
#define EXP2F(x) __builtin_amdgcn_exp2f(x)
#else
#define EXP2F(x) exp2f(x)
#endif

#if __has_builtin(__builtin_amdgcn_mfma_f32_16x16x16_bf16)
#define MFMA16(a,b,c) __builtin_amdgcn_mfma_f32_16x16x16_bf16(a,b,c,0,0,0)
#elif __has_builtin(__builtin_amdgcn_mfma_f32_16x16x16bf16_1k)
#define MFMA16(a,b,c) __builtin_amdgcn_mfma_f32_16x16x16bf16_1k(a,b,c,0,0,0)
#else
static __device__ __forceinline__ f32x4 mfma16_asm(short4_t a, short4_t b, f32x4 c){
  __asm__("v_mfma_f32_16x16x16_bf16 %0, %1, %2, %3" : "=v"(c) : "v"(a), "v"(b), "0"(c));
  return c;
}
#define MFMA16(a,b,c) mfma16_asm(a,b,c)
#endif

__device__ __forceinline__ void async16(const void* g, void* l){
  __builtin_amdgcn_global_load_lds((const __attribute__((address_space(1))) void*)g,
                                   (__attribute__((address_space(3))) void*)l, 16, 0, 0);
}

// pack 4 fp32 (in [0,1]) -> 4 bf16 (round-half-up) as K=16 A-fragment regs
__device__ __forceinline__ short4_t pack4(f32x4 s){
  unsigned u0 = (__float_as_uint(s[0]) + 0x8000u) >> 16;
  unsigned u1 = (__float_as_uint(s[1]) + 0x8000u) & 0xffff0000u;
  unsigned u2 = (__float_as_uint(s[2]) + 0x8000u) >> 16;
  unsigned u3 = (__float_as_uint(s[3]) + 0x8000u) & 0xffff0000u;
  union { unsigned v[2]; short4_t s4; } r;
  r.v[0] = u0 | u1; r.v[1] = u2 | u3;
  return r.s4;
}

// ---------------- LayerNorm (E=1024, one block per row) ----------------
template<int IN_F32>
__global__ __launch_bounds__(256) void ln_kernel(const void* __restrict__ xin,
    const float* __restrict__ g, const float* __restrict__ b, u16* __restrict__ y)
{
  const int E = 1024;
  int row = blockIdx.x, t = threadIdx.x;
  float f0,f1,f2,f3;
  if (IN_F32){
    const float* xr = (const float*)xin + (size_t)row*E;
    float4 xv = *(const float4*)(xr + t*4);
    f0=xv.x; f1=xv.y; f2=xv.z; f3=xv.w;
  } else {
    const u16* xr = (const u16*)xin + (size_t)row*E;
    ushort4 xv = *(const ushort4*)(xr + t*4);
    f0=b2f(xv.x); f1=b2f(xv.y); f2=b2f(xv.z); f3=b2f(xv.w);
  }
  float s1 = f0+f1+f2+f3;
  float s2 = f0*f0+f1*f1+f2*f2+f3*f3;
  #pragma unroll
  for (int off=32; off>=1; off>>=1){ s1 += __shfl_xor(s1,off); s2 += __shfl_xor(s2,off); }
  __shared__ float red[8];
  int w = t>>6;
  if ((t&63)==0){ red[w]=s1; red[4+w]=s2; }
  __syncthreads();
  float S1 = red[0]+red[1]+red[2]+red[3];
  float S2 = red[4]+red[5]+red[6]+red[7];
  float mean = S1*(1.0f/E);
  float var  = S2*(1.0f/E) - mean*mean;
  float inv  = rsqrtf(var + 1e-5f);
  float4 gv = *(const float4*)(g + t*4);
  float4 bv = *(const float4*)(b + t*4);
  ushort4 o;
  o.x = f2b((f0-mean)*inv*gv.x+bv.x);
  o.y = f2b((f1-mean)*inv*gv.y+bv.y);
  o.z = f2b((f2-mean)*inv*gv.z+bv.z);
  o.w = f2b((f3-mean)*inv*gv.w+bv.w);
  *(ushort4*)(y + (size_t)row*E + t*4) = o;
}

// ---------------- fp32->bf16 64x64-tiled transpose ----------------
__global__ __launch_bounds__(256) void transpose_bt(const float* __restrict__ src, u16* __restrict__ dst,
                                                    int ld_src, int ld_dst)
{
  __shared__ u16 tile[64*66];
  int c0 = blockIdx.x*64, r0 = blockIdx.y*64;
  int t = threadIdx.x;
  #pragma unroll
  for (int i=0;i<16;++i){
    int lin = i*256 + t;
    int rr = lin>>6, cc = lin&63;
    tile[cc*66+rr] = f2b(src[(size_t)(r0+rr)*ld_src + c0+cc]);
  }
  __syncthreads();
  #pragma unroll
  for (int i=0;i<16;++i){
    int lin = i*256 + t;
    int cc = lin>>6, rr = lin&63;
    dst[(size_t)(c0+cc)*ld_dst + r0+rr] = tile[cc*66+rr];
  }
}

// ---------------- QKV weight repack ----------------
__global__ __launch_bounds__(256) void qkv_repack(const float* __restrict__ wq, const float* __restrict__ wk,
                                                  const float* __restrict__ wv, u16* __restrict__ dst)
{
  __shared__ u16 tile[64*66];
  int e0 = blockIdx.x*64;
  int sel = blockIdx.y>>4, h = blockIdx.y&15;
  const float* src = (sel==0?wq:(sel==1?wk:wv)) + (size_t)h*1024*64;
  int t = threadIdx.x;
  #pragma unroll
  for (int i=0;i<16;++i){
    int lin=i*256+t; int rr=lin>>6, cc=lin&63;
    tile[cc*66+rr] = f2b(src[(size_t)(e0+rr)*64 + cc]);
  }
  __syncthreads();
  #pragma unroll
  for (int i=0;i<16;++i){
    int lin=i*256+t; int cc=lin>>6, rr=lin&63;
    dst[(size_t)(sel*1024 + h*64 + cc)*1024 + e0+rr] = tile[cc*66+rr];
  }
}

// ---------------- V transpose: qkv V-slice -> VT[bh][64][2048] ----------------
__global__ __launch_bounds__(256) void vtrans(const u16* __restrict__ qkv, u16* __restrict__ VT)
{
  __shared__ u16 tile[64*66];
  int bh = blockIdx.y, bb = bh>>4, h = bh&15;
  int s0 = blockIdx.x*64;
  const u16* src = qkv + ((size_t)(bb*2048) + s0)*3072 + 2048 + h*64;
  int t = threadIdx.x;
  int sr = t>>3, c0 = (t&7)*8;
  #pragma unroll
  for (int half=0; half<2; ++half){
    const u16* p = src + (size_t)(sr+half*32)*3072 + c0;
    ushort4 v0 = *(const ushort4*)p;
    ushort4 v1 = *(const ushort4*)(p+4);
    uint* d = (uint*)(tile + (sr+half*32)*66 + c0);
    d[0] = (uint)v0.x | ((uint)v0.y<<16);
    d[1] = (uint)v0.z | ((uint)v0.w<<16);
    d[2] = (uint)v1.x | ((uint)v1.y<<16);
    d[3] = (uint)v1.z | ((uint)v1.w<<16);
  }
  __syncthreads();
  u16* out = VT + (size_t)bh*64*2048 + s0;
  int dw = t>>3, sc = (t&7)*8;
  #pragma unroll
  for (int half=0; half<2; ++half){
    int d = dw + half*32;
    short8 pk;
    #pragma unroll
    for (int j=0;j<8;++j) pk[j] = (short)tile[(sc+j)*66 + d];
    *(short8*)(out + (size_t)d*2048 + sc) = pk;
  }
}

// ---------------- bf16 GEMM: C[M][N] = A[M][K] * Bt[N][K]^T (legacy 2-phase) ----------------
template<int MI>
__global__ __launch_bounds__(256, 3) void gemm_bt(const u16* __restrict__ A, const u16* __restrict__ Bt,
    u16* __restrict__ C, float* __restrict__ Cf, int M, int N, int K,
    const float* __restrict__ bias, const u16* __restrict__ residual, int do_relu, int gx)
{
  __shared__ __align__(16) u16 As[2][MI*32*64];
  __shared__ __align__(16) u16 Bs[2][128*64];
  int t = threadIdx.x;
  int bid = blockIdx.y * gridDim.x + blockIdx.x;
  int xcd = bid & 7, slot = bid >> 3;
  int gy = 8 / gx;
  int rx = gridDim.x / gx, ry = gridDim.y / gy;
  int col_b = (xcd % gx) * rx + (slot % rx);
  int row_b = (xcd / gx) * ry + (slot / rx);
  int row0 = row_b*(MI*32), col0 = col_b*128;
  int l = t&63, w = t>>6;
  int wm = (w>>1)*(MI*16), wn = (w&1)*64;
  int lr = l&15, lq = l>>4;
  (void)M;

  f32x4 acc[MI][4];
  #pragma unroll
  for (int i=0;i<MI;++i)
    #pragma unroll
    for (int j=0;j<4;++j) acc[i][j] = f32x4{0.f,0.f,0.f,0.f};

  const u16* gA = A  + (size_t)(row0 + (t>>3))*K + (((t&7)^((t>>3)&7))<<3);
  const u16* gB = Bt + (size_t)(col0 + (t>>3))*K + (((t&7)^((t>>3)&7))<<3);
  const size_t rnd = (size_t)32*K;
  int nk = K>>6;

  #pragma unroll
  for (int r=0;r<MI;++r) async16(gA + r*rnd, As[0] + r*2048 + t*8);
  #pragma unroll
  for (int r=0;r<4;++r)  async16(gB + r*rnd, Bs[0] + r*2048 + t*8);

  int sw8 = (lr&7);
  for (int kt=0; kt<nk; ++kt){
    int cur = kt&1;
    __syncthreads();
    if (kt+1 < nk){
      int ko = (kt+1)<<6;
      #pragma unroll
      for (int r=0;r<MI;++r) async16(gA + r*rnd + ko, As[cur^1] + r*2048 + t*8);
      #pragma unroll
      for (int r=0;r<4;++r)  async16(gB + r*rnd + ko, Bs[cur^1] + r*2048 + t*8);
    }
    const u16* as = As[cur];
    const u16* bs = Bs[cur];
    #pragma unroll
    for (int kk=0;kk<2;++kk){
      int so = (((kk*4+lq)^sw8))<<3;
      short8 a[MI], b[4];
      #pragma unroll
      for (int i=0;i<MI;++i) a[i] = *(const short8*)(as + (wm+i*16+lr)*64 + so);
      #pragma unroll
      for (int j=0;j<4;++j)  b[j] = *(const short8*)(bs + (wn+j*16+lr)*64 + so);
      #pragma unroll
      for (int i=0;i<MI;++i)
        #pragma unroll
        for (int j=0;j<4;++j)
          acc[i][j] = __builtin_amdgcn_mfma_f32_16x16x32_bf16(a[i], b[j], acc[i][j], 0,0,0);
    }
  }

  #pragma unroll
  for (int i=0;i<MI;++i){
    #pragma unroll
    for (int j=0;j<4;++j){
      int col = col0 + wn + j*16 + lr;
      float bv = bias ? bias[col] : 0.0f;
      #pragma unroll
      for (int r=0;r<4;++r){
        int row = row0 + wm + i*16 + lq*4 + r;
        float v = acc[i][j][r] + bv;
        if (do_relu) v = fmaxf(v, 0.0f);
        if (residual) v += b2f(residual[(size_t)row*N + col]);
        if (Cf) Cf[(size_t)row*N + col] = v;
        else    C [(size_t)row*N + col] = f2b(v);
      }
    }
  }
}

// ---------------- gemm256a: v1 schedule (passed r2/r3) — reads BEFORE MFMA each phase ----
__global__ __launch_bounds__(512,2) void gemm256a(const u16* __restrict__ A, const u16* __restrict__ Bt,
    u16* __restrict__ C, float* __restrict__ Cf, int N, int K,
    const float* __restrict__ bias, const u16* __restrict__ residual, int do_relu, int gx)
{
  __shared__ __align__(16) u16 As[2][256*64];
  __shared__ __align__(16) u16 Bs[2][256*64];
  int t = threadIdx.x;
  int bid = blockIdx.y*gridDim.x + blockIdx.x;
  int xcd = bid & 7, slot = bid >> 3;
  int gy = 8/gx;
  int rx = gridDim.x/gx, ry = gridDim.y/gy;
  int col_b = (xcd%gx)*rx + slot%rx;
  int row_b = (xcd/gx)*ry + slot/rx;
  int row0 = row_b*256, col0 = col_b*256;
  int l = t&63, w = t>>6;
  int wr = w>>2, wc = w&3;           // 2 x 4 wave grid, per-wave 128(M) x 64(N)
  int lr = l&15, lq = l>>4, sw = lr&7;

  f32x4 acc[8][4];
  #pragma unroll
  for (int m=0;m<8;++m)
    #pragma unroll
    for (int n=0;n<4;++n) acc[m][n] = f32x4{0.f,0.f,0.f,0.f};

  int i = t>>3, c8 = t&7;
  int swc = (c8 ^ (i&7))*8;
  const u16* aS[4]; const u16* bS[4];
  {
    int la[4] = { i, 128+i, 64+i, 192+i };
    #pragma unroll
    for (int s=0;s<4;++s){
      aS[s] = A + (size_t)(row0 + la[s])*K + swc;
      int p = s*64 + i;
      int lb = ((p>>5)&3)*64 + (p>>7)*32 + (p&31);
      bS[s] = Bt + (size_t)(col0 + lb)*K + swc;
    }
  }
  int nk = K>>6;

  async16(aS[0], As[0] + 0*4096 + t*8);
  async16(aS[1], As[0] + 1*4096 + t*8);
  async16(bS[0], Bs[0] + 0*4096 + t*8);
  async16(bS[1], Bs[0] + 1*4096 + t*8);
  async16(bS[2], Bs[0] + 2*4096 + t*8);
  async16(bS[3], Bs[0] + 3*4096 + t*8);
  async16(aS[2], As[0] + 2*4096 + t*8);
  async16(aS[3], As[0] + 3*4096 + t*8);
  asm volatile("s_waitcnt vmcnt(4)" ::: "memory");
  __builtin_amdgcn_s_barrier();

  short8 af[4][2], bf[2][2];

#define RD_A(qm) \
  _Pragma("unroll") \
  for (int mm=0;mm<4;++mm){ \
    _Pragma("unroll") \
    for (int kk=0;kk<2;++kk) \
      af[mm][kk] = *(const short8*)(asC + ((qm)*128 + wr*64 + mm*16 + lr)*64 + (((kk*4+lq)^sw)<<3)); \
  }
#define RD_B(qn) \
  _Pragma("unroll") \
  for (int nn=0;nn<2;++nn){ \
    _Pragma("unroll") \
    for (int kk=0;kk<2;++kk) \
      bf[nn][kk] = *(const short8*)(bsC + ((qn)*128 + wc*32 + nn*16 + lr)*64 + (((kk*4+lq)^sw)<<3)); \
  }
#define MMQ(qm,qn) \
  __builtin_amdgcn_s_setprio(1); \
  _Pragma("unroll") \
  for (int mm=0;mm<4;++mm){ \
    _Pragma("unroll") \
    for (int nn=0;nn<2;++nn){ \
      _Pragma("unroll") \
      for (int kk=0;kk<2;++kk) \
        acc[(qm)*4+mm][(qn)*2+nn] = __builtin_amdgcn_mfma_f32_16x16x32_bf16(af[mm][kk], bf[nn][kk], acc[(qm)*4+mm][(qn)*2+nn], 0,0,0); \
    } \
  } \
  __builtin_amdgcn_s_setprio(0);
#define BARW \
  __builtin_amdgcn_s_barrier(); \
  asm volatile("s_waitcnt lgkmcnt(0)" ::: "memory"); \
  __builtin_amdgcn_sched_barrier(0);
#define PIN __builtin_amdgcn_sched_barrier(0);

  for (int kt=0; kt<nk-1; ++kt){
    int cur = kt&1;
    const u16* asC = As[cur]; const u16* bsC = Bs[cur];
    u16* asN = As[cur^1];    u16* bsN = Bs[cur^1];
    int ko = (kt+1)<<6;
    RD_A(0); RD_B(0);
    async16(aS[0]+ko, asN + 0*4096 + t*8);
    async16(aS[1]+ko, asN + 1*4096 + t*8);
    PIN;
    asm volatile("s_waitcnt vmcnt(4)" ::: "memory");
    BARW;
    MMQ(0,0);
    __builtin_amdgcn_s_barrier();
    RD_B(1);
    async16(bS[0]+ko, bsN + 0*4096 + t*8);
    async16(bS[1]+ko, bsN + 1*4096 + t*8);
    PIN;
    asm volatile("s_waitcnt vmcnt(4)" ::: "memory");
    BARW;
    MMQ(0,1);
    __builtin_amdgcn_s_barrier();
    RD_A(1);
    async16(bS[2]+ko, bsN + 2*4096 + t*8);
    async16(bS[3]+ko, bsN + 3*4096 + t*8);
    PIN;
    BARW;
    MMQ(1,1);
    __builtin_amdgcn_s_barrier();
    RD_B(0);
    async16(aS[2]+ko, asN + 2*4096 + t*8);
    async16(aS[3]+ko, asN + 3*4096 + t*8);
    PIN;
    asm volatile("s_waitcnt vmcnt(4)" ::: "memory");
    BARW;
    MMQ(1,0);
    __builtin_amdgcn_s_barrier();
  }
  {
    int cur = (nk-1)&1;
    const u16* asC = As[cur]; const u16* bsC = Bs[cur];
    RD_A(0); RD_B(0);
    asm volatile("s_waitcnt vmcnt(2)" ::: "memory");
    BARW;
    MMQ(0,0);
    __builtin_amdgcn_s_barrier();
    RD_B(1);
    asm volatile("s_waitcnt vmcnt(0)" ::: "memory");
    BARW;
    MMQ(0,1);
    __builtin_amdgcn_s_barrier();
    RD_A(1);
    BARW;
    MMQ(1,1);
    __builtin_amdgcn_s_barrier();
    RD_B(0);
    BARW;
    MMQ(1,0);
  }
#undef RD_A
#undef RD_B
#undef MMQ
#undef BARW
#undef PIN

  #pragma unroll
  for (int m=0;m<8;++m){
    #pragma unroll
    for (int n=0;n<4;++n){
      int col = col0 + wc*64 + n*16 + lr;
      float bv = bias ? bias[col] : 0.0f;
      #pragma unroll
      for (int r=0;r<4;++r){
        int row = row0 + wr*128 + m*16 + lq*4 + r;
        float v = acc[m][n][r] + bv;
        if (do_relu) v = fmaxf(v, 0.0f);
        if (residual) v += b2f(residual[(size_t)row*N + col]);
        if (Cf) Cf[(size_t)row*N + col] = v;
        else    C [(size_t)row*N + col] = f2b(v);
      }
    }
  }
}

// ---------------- gemm256b: v2 schedule — reads AFTER MFMA (consumed next phase) ----
__global__ __launch_bounds__(512,2) void gemm256b(const u16* __restrict__ A, const u16* __restrict__ Bt,
    u16* __restrict__ C, float* __restrict__ Cf, int N, int K,
    const float* __restrict__ bias, const u16* __restrict__ residual, int do_relu, int gx)
{
  __shared__ __align__(16) u16 As[2][256*64];
  __shared__ __align__(16) u16 Bs[2][256*64];
  int t = threadIdx.x;
  int bid = blockIdx.y*gridDim.x + blockIdx.x;
  int xcd = bid & 7, slot = bid >> 3;
  int gy = 8/gx;
  int rx = gridDim.x/gx, ry = gridDim.y/gy;
  int col_b = (xcd%gx)*rx + slot%rx;
  int row_b = (xcd/gx)*ry + slot/rx;
  int row0 = row_b*256, col0 = col_b*256;
  int l = t&63, w = t>>6;
  int wr = w>>2, wc = w&3;
  int lr = l&15, lq = l>>4, sw = lr&7;

  f32x4 acc[8][4];
  #pragma unroll
  for (int m=0;m<8;++m)
    #pragma unroll
    for (int n=0;n<4;++n) acc[m][n] = f32x4{0.f,0.f,0.f,0.f};

  int i = t>>3, c8 = t&7;
  int swc = (c8 ^ (i&7))*8;
  const u16* aS[4]; const u16* bS[4];
  {
    int la[4] = { i, 128+i, 64+i, 192+i };
    #pragma unroll
    for (int s=0;s<4;++s){
      aS[s] = A + (size_t)(row0 + la[s])*K + swc;
      int p = s*64 + i;
      int lb = ((p>>5)&3)*64 + (p>>7)*32 + (p&31);
      bS[s] = Bt + (size_t)(col0 + lb)*K + swc;
    }
  }
  int nk = K>>6;   // requires nk even, >=4

  u16* A0b = As[0]; u16* A1b = As[1];
  u16* B0b = Bs[0]; u16* B1b = Bs[1];

  async16(aS[0], A0b + 0*4096 + t*8);
  async16(aS[1], A0b + 1*4096 + t*8);
  async16(bS[0], B0b + 0*4096 + t*8);
  async16(bS[1], B0b + 1*4096 + t*8);
  async16(bS[2], B0b + 2*4096 + t*8);
  async16(bS[3], B0b + 3*4096 + t*8);
  async16(aS[2], A0b + 2*4096 + t*8);
  async16(aS[3], A0b + 3*4096 + t*8);

  short8 af[4][2], b0f[2][2], b1f[2][2];

#define VM4  asm volatile("s_waitcnt vmcnt(4)" ::: "memory");
#define VM2  asm volatile("s_waitcnt vmcnt(2)" ::: "memory");
#define VM0  asm volatile("s_waitcnt vmcnt(0)" ::: "memory");
#define LGK  asm volatile("s_waitcnt lgkmcnt(0)" ::: "memory");
#define BAR  __builtin_amdgcn_s_barrier();
#define PIN  __builtin_amdgcn_sched_barrier(0);

#define RD_A(BUF,qm) \
  _Pragma("unroll") \
  for (int mm=0;mm<4;++mm){ \
    _Pragma("unroll") \
    for (int kk=0;kk<2;++kk) \
      af[mm][kk] = *(const short8*)((const u16*)(BUF) + ((qm)*128 + wr*64 + mm*16 + lr)*64 + (((kk*4+lq)^sw)<<3)); \
  }
#define RD_B(DST,BUF,qn) \
  _Pragma("unroll") \
  for (int nn=0;nn<2;++nn){ \
    _Pragma("unroll") \
    for (int kk=0;kk<2;++kk) \
      DST[nn][kk] = *(const short8*)((const u16*)(BUF) + ((qn)*128 + wc*32 + nn*16 + lr)*64 + (((kk*4+lq)^sw)<<3)); \
  }
#define MMQ(qm,qn,BSS) \
  __builtin_amdgcn_s_setprio(1); \
  _Pragma("unroll") \
  for (int mm=0;mm<4;++mm){ \
    _Pragma("unroll") \
    for (int nn=0;nn<2;++nn){ \
      _Pragma("unroll") \
      for (int kk=0;kk<2;++kk) \
        acc[(qm)*4+mm][(qn)*2+nn] = __builtin_amdgcn_mfma_f32_16x16x32_bf16(af[mm][kk], BSS[nn][kk], acc[(qm)*4+mm][(qn)*2+nn], 0,0,0); \
    } \
  } \
  __builtin_amdgcn_s_setprio(0);

#define ITER(CA,CB,NA,NB,KO,BP,BQ) \
  async16(aS[0]+(KO), (NA) + 0*4096 + t*8); \
  async16(aS[1]+(KO), (NA) + 1*4096 + t*8); \
  PIN; VM4; BAR; LGK; PIN; \
  MMQ(0,0,BP); \
  RD_B(BQ,CB,1); PIN; \
  BAR; \
  async16(bS[0]+(KO), (NB) + 0*4096 + t*8); \
  async16(bS[1]+(KO), (NB) + 1*4096 + t*8); \
  PIN; VM4; BAR; LGK; PIN; \
  MMQ(0,1,BQ); \
  RD_A(CA,1); PIN; \
  BAR; \
  async16(bS[2]+(KO), (NB) + 2*4096 + t*8); \
  async16(bS[3]+(KO), (NB) + 3*4096 + t*8); \
  PIN; BAR; LGK; PIN; \
  MMQ(1,1,BQ); \
  BAR; \
  async16(aS[2]+(KO), (NA) + 2*4096 + t*8); \
  async16(aS[3]+(KO), (NA) + 3*4096 + t*8); \
  PIN; VM4; BAR; LGK; PIN; \
  MMQ(1,0,BP); \
  RD_A(NA,0); RD_B(BQ,NB,0); PIN; \
  BAR;

#define PEEL(CA,CB,BP,BQ) \
  VM2; BAR; LGK; PIN; \
  MMQ(0,0,BP); \
  RD_B(BQ,CB,1); PIN; \
  BAR; \
  VM0; BAR; LGK; PIN; \
  MMQ(0,1,BQ); \
  RD_A(CA,1); PIN; \
  BAR; \
  LGK; PIN; \
  MMQ(1,1,BQ); \
  MMQ(1,0,BP);

  VM4; BAR;
  RD_A(A0b,0); RD_B(b0f,B0b,0); PIN;

  for (int kt=0; kt+2<nk; kt+=2){
    int ko1 = (kt+1)<<6, ko2 = (kt+2)<<6;
    ITER(A0b,B0b,A1b,B1b,ko1,b0f,b1f);
    ITER(A1b,B1b,A0b,B0b,ko2,b1f,b0f);
  }
  { int ko = (nk-1)<<6;
    ITER(A0b,B0b,A1b,B1b,ko,b0f,b1f);
  }
  PEEL(A1b,B1b,b1f,b0f);

#undef VM4
#undef VM2
#undef VM0
#undef LGK
#undef BAR
#undef PIN
#undef RD_A
#undef RD_B
#undef MMQ
#undef ITER
#undef PEEL

  #pragma unroll
  for (int m=0;m<8;++m){
    #pragma unroll
    for (int n=0;n<4;++n){
      int col = col0 + wc*64 + n*16 + lr;
      float bv = bias ? bias[col] : 0.0f;
      #pragma unroll
      for (int r=0;r<4;++r){
        int row = row0 + wr*128 + m*16 + lq*4 + r;
        float v = acc[m][n][r] + bv;
        if (do_relu) v = fmaxf(v, 0.0f);
        if (residual) v += b2f(residual[(size_t)row*N + col]);
        if (Cf) Cf[(size_t)row*N + col] = v;
        else    C [(size_t)row*N + col] = f2b(v);
      }
    }
  }
}

// ---------------- causal flash attention v4 ----------------
// Q-tile 64 (4 waves x 16 q rows), s-tile 64 double-buffered, grid 1024.
// S^T via K=32 mfma; P stays IN-LANE (C-layout == K=16 A-layout), PV via
// 16x16x16 mfma on packed bf16 — no P LDS round-trip. Complementary-qt
// slot pairing balances per-CU work. K and V^T staged via global_load_lds.
__global__ __launch_bounds__(256,4) void attn_kernel(const u16* __restrict__ QKV,
    const u16* __restrict__ VT, u16* __restrict__ O)
{
  const int T=2048, LD=3072, E=1024;
  int bid = blockIdx.y * gridDim.x + blockIdx.x;
  int xcd = bid & 7, slot = bid >> 3;
  int idx = slot & 31, grp = slot >> 5;
  int qt = (grp & 1) ? idx : 31 - idx;   // heavy-first, complementary pairing
  int bh = xcd*4 + grp;
  int bb = bh>>4, h = bh&15;
  const u16* base = QKV + (size_t)bb*T*LD;
  const u16* Qp = base + h*64;
  const u16* Kp = base + 1024 + h*64;
  const u16* Vtp = VT + (size_t)bh*64*2048;
  int t = threadIdx.x, l = t&63, w = t>>6;
  int lr = l&15, lq = l>>4;

  __shared__ __align__(16) u16 Ks[2][64*64];   // [s][d], chunk c at slot c^(s&7)
  __shared__ __align__(16) u16 Vs[2][64*64];   // [d][s], chunk c at slot c^(d&7)

  const float QSC = 0.125f*1.44269504f;
  int q0 = qt*64 + w*16;
  short8 aq[2];
  #pragma unroll
  for (int kk=0;kk<2;++kk){
    short8 raw = *(const short8*)(Qp + (size_t)(q0+lr)*LD + kk*32 + lq*8);
    short8 sc;
    #pragma unroll
    for (int j=0;j<8;++j) sc[j] = (short)f2b(b2f((u16)raw[j])*QSC);
    aq[kk]=sc;
  }

  float mrun = -3e38f, lrun = 0.f;
  f32x4 Oacc[4];
  #pragma unroll
  for (int dt=0;dt<4;++dt) Oacc[dt] = f32x4{0.f,0.f,0.f,0.f};

  int kc = (l&7) ^ (l>>3);
  int ra = 8*w + (l>>3);

  // prologue: stage tile 0
  async16(Kp  + (size_t)ra*LD        + kc*8, Ks[0] + t*8);
  async16(Kp  + (size_t)(ra+32)*LD   + kc*8, Ks[0] + 2048 + t*8);
  async16(Vtp + (size_t)ra*2048      + kc*8, Vs[0] + t*8);
  async16(Vtp + (size_t)(ra+32)*2048 + kc*8, Vs[0] + 2048 + t*8);

  for (int it=0; it<=qt; ++it){
    int s0 = it*64, cur = it&1;
    __syncthreads();
    if (it < qt){
      int sn = s0+64;
      u16* kd = Ks[cur^1]; u16* vd = Vs[cur^1];
      async16(Kp  + (size_t)(sn+ra)*LD        + kc*8, kd + t*8);
      async16(Kp  + (size_t)(sn+ra+32)*LD     + kc*8, kd + 2048 + t*8);
      async16(Vtp + (size_t)ra*2048      + sn + kc*8, vd + t*8);
      async16(Vtp + (size_t)(ra+32)*2048 + sn + kc*8, vd + 2048 + t*8);
    }
    const u16* ks = Ks[cur];
    const u16* vs = Vs[cur];

    // S^T[s][q] for this wave's 16 q
    f32x4 S[4];
    #pragma unroll
    for (int st=0; st<4; ++st){
      short8 kf0 = *(const short8*)(ks + (st*16+lr)*64 + ((lq  )^(lr&7))*8);
      short8 kf1 = *(const short8*)(ks + (st*16+lr)*64 + ((4+lq)^(lr&7))*8);
      f32x4 z = f32x4{0.f,0.f,0.f,0.f};
      z = __builtin_amdgcn_mfma_f32_16x16x32_bf16(kf0, aq[0], z, 0,0,0);
      z = __builtin_amdgcn_mfma_f32_16x16x32_bf16(kf1, aq[1], z, 0,0,0);
      S[st] = z;
    }
    if (it == qt){
      int qg = q0 + lr;
      #pragma unroll
      for (int st=0;st<4;++st)
        #pragma unroll
        for (int r=0;r<4;++r){
          int sg = s0 + st*16 + lq*4 + r;
          if (sg > qg) S[st][r] = -3e38f;
        }
    }
    // online softmax (q = lr; s-reduction in-lane + 2 shuffles)
    float m = S[0][0];
    #pragma unroll
    for (int st=0;st<4;++st)
      #pragma unroll
      for (int r=0;r<4;++r) m = fmaxf(m, S[st][r]);
    m = fmaxf(m, __shfl_xor(m,16));
    m = fmaxf(m, __shfl_xor(m,32));
    float mnew = fmaxf(mrun, m);
    float alpha = EXP2F(mrun - mnew);
    mrun = mnew;
    float ssum = 0.f;
    #pragma unroll
    for (int st=0;st<4;++st)
      #pragma unroll
      for (int r=0;r<4;++r){ float p = EXP2F(S[st][r]-mnew); S[st][r]=p; ssum+=p; }
    ssum += __shfl_xor(ssum,16);
    ssum += __shfl_xor(ssum,32);
    lrun = lrun*alpha + ssum;
    // P: in-lane pack to K=16 A-fragments
    short4_t pk[4];
    #pragma unroll
    for (int st=0;st<4;++st) pk[st] = pack4(S[st]);
    // rescale O (O rows: q = lq*4+r)
    float af[4];
    #pragma unroll
    for (int r=0;r<4;++r) af[r] = __shfl(alpha, lq*4+r);
    #pragma unroll
    for (int dt=0;dt<4;++dt)
      #pragma unroll
      for (int r=0;r<4;++r) Oacc[dt][r] *= af[r];
    // PV: 16 x mfma_16x16x16
    #pragma unroll
    for (int st=0;st<4;++st){
      #pragma unroll
      for (int dt=0;dt<4;++dt){
        short4_t vf = *(const short4_t*)(vs + (dt*16+lr)*64 + ((2*st+(lq>>1))^(lr&7))*8 + (lq&1)*4);
        Oacc[dt] = MFMA16(pk[st], vf, Oacc[dt]);
      }
    }
  }
  float linv[4];
  #pragma unroll
  for (int r=0;r<4;++r) linv[r] = 1.0f/__shfl(lrun, lq*4+r);
  #pragma unroll
  for (int dt=0;dt<4;++dt)
    #pragma unroll
    for (int r=0;r<4;++r){
      int qg = q0 + lq*4 + r;
      O[(size_t)(bb*T+qg)*E + h*64 + dt*16 + lr] = f2b(Oacc[dt][r]*linv[r]);
    }
}

// ---------------- host ----------------
extern "C" void kernel_launch(void* const* d_in, const int* in_sizes, int n_in,
                              void* d_out, int out_size, void* d_ws, size_t ws_size,
                              hipStream_t stream)
{
  (void)in_sizes; (void)n_in; (void)out_size; (void)ws_size;
  const float* x     = (const float*)d_in[0];
  const float* wq    = (const float*)d_in[1];
  const float* wk    = (const float*)d_in[2];
  const float* wv    = (const float*)d_in[3];
  const float* wproj = (const float*)d_in[4];
  const float* bproj = (const float*)d_in[5];
  const float* g1    = (const float*)d_in[6];
  const float* be1   = (const float*)d_in[7];
  const float* g2    = (const float*)d_in[8];
  const float* be2   = (const float*)d_in[9];
  const float* w1    = (const float*)d_in[10];
  const float* b1    = (const float*)d_in[11];
  const float* w2    = (const float*)d_in[12];
  const float* b2    = (const float*)d_in[13];
  float* out = (float*)d_out;

  char* ws = (char*)d_ws;
  size_t off = 0;
  auto alloc = [&](size_t bytes)->void*{ void* p = ws + off; off += (bytes + 255) & ~(size_t)255; return p; };
  u16* hnorm  = (u16*)alloc((size_t)4096*1024*2);
  u16* qkv    = (u16*)alloc((size_t)4096*3072*2);
  u16* VT     = (u16*)alloc((size_t)32*64*2048*2);
  u16* attnO  = (u16*)alloc((size_t)4096*1024*2);
  u16* x2     = (u16*)alloc((size_t)4096*1024*2);
  u16* h2     = (u16*)alloc((size_t)4096*1024*2);
  u16* ffn1   = (u16*)alloc((size_t)4096*4096*2);
  u16* wqkvT  = (u16*)alloc((size_t)3072*1024*2);
  u16* wprojT = (u16*)alloc((size_t)1024*1024*2);
  u16* w1T    = (u16*)alloc((size_t)4096*1024*2);
  u16* w2T    = (u16*)alloc((size_t)1024*4096*2);

  qkv_repack  <<<dim3(16,48),256,0,stream>>>(wq,wk,wv,wqkvT);
  transpose_bt<<<dim3(16,16),256,0,stream>>>(wproj, wprojT, 1024, 1024);
  transpose_bt<<<dim3(64,16),256,0,stream>>>(w1,    w1T,    4096, 1024);
  transpose_bt<<<dim3(16,64),256,0,stream>>>(w2,    w2T,    1024, 4096);

  ln_kernel<1><<<4096,256,0,stream>>>(x, g1, be1, hnorm);
  gemm256a<<<dim3(12,16),512,0,stream>>>(hnorm, wqkvT, qkv, nullptr, 3072, 1024, nullptr, nullptr, 0, 4);
  vtrans<<<dim3(32,32),256,0,stream>>>(qkv, VT);
  attn_kernel<<<dim3(32,32),256,0,stream>>>(qkv, VT, attnO);
  gemm_bt<2><<<dim3(8,64),256,0,stream>>>(attnO, wprojT, x2, nullptr, 4096,1024,1024, bproj, hnorm, 0, 2);
  ln_kernel<0><<<4096,256,0,stream>>>(x2, g2, be2, h2);
  gemm256b<<<dim3(16,16),512,0,stream>>>(h2, w1T, ffn1, nullptr, 4096, 1024, b1, nullptr, 1, 4);
  gemm_bt<2><<<dim3(8,64),256,0,stream>>>(ffn1, w2T, nullptr, out, 4096,1024,4096, b2, h2, 0, 2);
}

// Round 7
// 361.253 us; speedup vs baseline: 1.0904x; 1.0136x over previous
//
#include <hip/hip_runtime.h>
#include <stdint.h>

typedef unsigned short u16;
typedef __attribute__((ext_vector_type(8))) short short8;
typedef __attribute__((ext_vector_type(4))) short short4_t;
typedef __attribute__((ext_vector_type(4))) float f32x4;

__device__ __forceinline__ float b2f(u16 u){ union{unsigned i; float f;}v; v.i=((unsigned)u)<<16; return v.f; }
__device__ __forceinline__ u16 f2b(float f){ unsigned x=__float_as_uint(f); return (u16)((x + 0x7fffu + ((x>>16)&1u))>>16); }

#if __has_builtin(__builtin_amdgcn_exp2f)
#define EXP2F(x) __builtin_amdgcn_exp2f(x)
#else
#define EXP2F(x) exp2f(x)
#endif

#if __has_builtin(__builtin_amdgcn_mfma_f32_16x16x16_bf16)
#define MFMA16(a,b,c) __builtin_amdgcn_mfma_f32_16x16x16_bf16(a,b,c,0,0,0)
#elif __has_builtin(__builtin_amdgcn_mfma_f32_16x16x16bf16_1k)
#define MFMA16(a,b,c) __builtin_amdgcn_mfma_f32_16x16x16bf16_1k(a,b,c,0,0,0)
#else
static __device__ __forceinline__ f32x4 mfma16_asm(short4_t a, short4_t b, f32x4 c){
  __asm__("v_mfma_f32_16x16x16_bf16 %0, %1, %2, %3" : "=v"(c) : "v"(a), "v"(b), "0"(c));
  return c;
}
#define MFMA16(a,b,c) mfma16_asm(a,b,c)
#endif

__device__ __forceinline__ void async16(const void* g, void* l){
  __builtin_amdgcn_global_load_lds((const __attribute__((address_space(1))) void*)g,
                                   (__attribute__((address_space(3))) void*)l, 16, 0, 0);
}

// pack 4 fp32 (in [0,1]) -> 4 bf16 (round-half-up) as K=16 A-fragment regs
__device__ __forceinline__ short4_t pack4(f32x4 s){
  unsigned u0 = (__float_as_uint(s[0]) + 0x8000u) >> 16;
  unsigned u1 = (__float_as_uint(s[1]) + 0x8000u) & 0xffff0000u;
  unsigned u2 = (__float_as_uint(s[2]) + 0x8000u) >> 16;
  unsigned u3 = (__float_as_uint(s[3]) + 0x8000u) & 0xffff0000u;
  union { unsigned v[2]; short4_t s4; } r;
  r.v[0] = u0 | u1; r.v[1] = u2 | u3;
  return r.s4;
}

// ---------------- LayerNorm (E=1024, one block per row) ----------------
template<int IN_F32>
__global__ __launch_bounds__(256) void ln_kernel(const void* __restrict__ xin,
    const float* __restrict__ g, const float* __restrict__ b, u16* __restrict__ y)
{
  const int E = 1024;
  int row = blockIdx.x, t = threadIdx.x;
  float f0,f1,f2,f3;
  if (IN_F32){
    const float* xr = (const float*)xin + (size_t)row*E;
    float4 xv = *(const float4*)(xr + t*4);
    f0=xv.x; f1=xv.y; f2=xv.z; f3=xv.w;
  } else {
    const u16* xr = (const u16*)xin + (size_t)row*E;
    ushort4 xv = *(const ushort4*)(xr + t*4);
    f0=b2f(xv.x); f1=b2f(xv.y); f2=b2f(xv.z); f3=b2f(xv.w);
  }
  float s1 = f0+f1+f2+f3;
  float s2 = f0*f0+f1*f1+f2*f2+f3*f3;
  #pragma unroll
  for (int off=32; off>=1; off>>=1){ s1 += __shfl_xor(s1,off); s2 += __shfl_xor(s2,off); }
  __shared__ float red[8];
  int w = t>>6;
  if ((t&63)==0){ red[w]=s1; red[4+w]=s2; }
  __syncthreads();
  float S1 = red[0]+red[1]+red[2]+red[3];
  float S2 = red[4]+red[5]+red[6]+red[7];
  float mean = S1*(1.0f/E);
  float var  = S2*(1.0f/E) - mean*mean;
  float inv  = rsqrtf(var + 1e-5f);
  float4 gv = *(const float4*)(g + t*4);
  float4 bv = *(const float4*)(b + t*4);
  ushort4 o;
  o.x = f2b((f0-mean)*inv*gv.x+bv.x);
  o.y = f2b((f1-mean)*inv*gv.y+bv.y);
  o.z = f2b((f2-mean)*inv*gv.z+bv.z);
  o.w = f2b((f3-mean)*inv*gv.w+bv.w);
  *(ushort4*)(y + (size_t)row*E + t*4) = o;
}

// ---------------- fp32->bf16 64x64-tiled transpose ----------------
__global__ __launch_bounds__(256) void transpose_bt(const float* __restrict__ src, u16* __restrict__ dst,
                                                    int ld_src, int ld_dst)
{
  __shared__ u16 tile[64*66];
  int c0 = blockIdx.x*64, r0 = blockIdx.y*64;
  int t = threadIdx.x;
  #pragma unroll
  for (int i=0;i<16;++i){
    int lin = i*256 + t;
    int rr = lin>>6, cc = lin&63;
    tile[cc*66+rr] = f2b(src[(size_t)(r0+rr)*ld_src + c0+cc]);
  }
  __syncthreads();
  #pragma unroll
  for (int i=0;i<16;++i){
    int lin = i*256 + t;
    int cc = lin>>6, rr = lin&63;
    dst[(size_t)(c0+cc)*ld_dst + r0+rr] = tile[cc*66+rr];
  }
}

// ---------------- QKV weight repack ----------------
__global__ __launch_bounds__(256) void qkv_repack(const float* __restrict__ wq, const float* __restrict__ wk,
                                                  const float* __restrict__ wv, u16* __restrict__ dst)
{
  __shared__ u16 tile[64*66];
  int e0 = blockIdx.x*64;
  int sel = blockIdx.y>>4, h = blockIdx.y&15;
  const float* src = (sel==0?wq:(sel==1?wk:wv)) + (size_t)h*1024*64;
  int t = threadIdx.x;
  #pragma unroll
  for (int i=0;i<16;++i){
    int lin=i*256+t; int rr=lin>>6, cc=lin&63;
    tile[cc*66+rr] = f2b(src[(size_t)(e0+rr)*64 + cc]);
  }
  __syncthreads();
  #pragma unroll
  for (int i=0;i<16;++i){
    int lin=i*256+t; int cc=lin>>6, rr=lin&63;
    dst[(size_t)(sel*1024 + h*64 + cc)*1024 + e0+rr] = tile[cc*66+rr];
  }
}

// ---------------- V transpose: qkv V-slice -> VT[bh][64][2048] ----------------
__global__ __launch_bounds__(256) void vtrans(const u16* __restrict__ qkv, u16* __restrict__ VT)
{
  __shared__ u16 tile[64*66];
  int bh = blockIdx.y, bb = bh>>4, h = bh&15;
  int s0 = blockIdx.x*64;
  const u16* src = qkv + ((size_t)(bb*2048) + s0)*3072 + 2048 + h*64;
  int t = threadIdx.x;
  int sr = t>>3, c0 = (t&7)*8;
  #pragma unroll
  for (int half=0; half<2; ++half){
    const u16* p = src + (size_t)(sr+half*32)*3072 + c0;
    ushort4 v0 = *(const ushort4*)p;
    ushort4 v1 = *(const ushort4*)(p+4);
    uint* d = (uint*)(tile + (sr+half*32)*66 + c0);
    d[0] = (uint)v0.x | ((uint)v0.y<<16);
    d[1] = (uint)v0.z | ((uint)v0.w<<16);
    d[2] = (uint)v1.x | ((uint)v1.y<<16);
    d[3] = (uint)v1.z | ((uint)v1.w<<16);
  }
  __syncthreads();
  u16* out = VT + (size_t)bh*64*2048 + s0;
  int dw = t>>3, sc = (t&7)*8;
  #pragma unroll
  for (int half=0; half<2; ++half){
    int d = dw + half*32;
    short8 pk;
    #pragma unroll
    for (int j=0;j<8;++j) pk[j] = (short)tile[(sc+j)*66 + d];
    *(short8*)(out + (size_t)d*2048 + sc) = pk;
  }
}

// ---------------- bf16 GEMM: C[M][N] = A[M][K] * Bt[N][K]^T (legacy 2-phase) ----------------
template<int MI>
__global__ __launch_bounds__(256, 3) void gemm_bt(const u16* __restrict__ A, const u16* __restrict__ Bt,
    u16* __restrict__ C, float* __restrict__ Cf, int M, int N, int K,
    const float* __restrict__ bias, const u16* __restrict__ residual, int do_relu, int gx)
{
  __shared__ __align__(16) u16 As[2][MI*32*64];
  __shared__ __align__(16) u16 Bs[2][128*64];
  int t = threadIdx.x;
  int bid = blockIdx.y * gridDim.x + blockIdx.x;
  int xcd = bid & 7, slot = bid >> 3;
  int gy = 8 / gx;
  int rx = gridDim.x / gx, ry = gridDim.y / gy;
  int col_b = (xcd % gx) * rx + (slot % rx);
  int row_b = (xcd / gx) * ry + (slot / rx);
  int row0 = row_b*(MI*32), col0 = col_b*128;
  int l = t&63, w = t>>6;
  int wm = (w>>1)*(MI*16), wn = (w&1)*64;
  int lr = l&15, lq = l>>4;
  (void)M;

  f32x4 acc[MI][4];
  #pragma unroll
  for (int i=0;i<MI;++i)
    #pragma unroll
    for (int j=0;j<4;++j) acc[i][j] = f32x4{0.f,0.f,0.f,0.f};

  const u16* gA = A  + (size_t)(row0 + (t>>3))*K + (((t&7)^((t>>3)&7))<<3);
  const u16* gB = Bt + (size_t)(col0 + (t>>3))*K + (((t&7)^((t>>3)&7))<<3);
  const size_t rnd = (size_t)32*K;
  int nk = K>>6;

  #pragma unroll
  for (int r=0;r<MI;++r) async16(gA + r*rnd, As[0] + r*2048 + t*8);
  #pragma unroll
  for (int r=0;r<4;++r)  async16(gB + r*rnd, Bs[0] + r*2048 + t*8);

  int sw8 = (lr&7);
  for (int kt=0; kt<nk; ++kt){
    int cur = kt&1;
    __syncthreads();
    if (kt+1 < nk){
      int ko = (kt+1)<<6;
      #pragma unroll
      for (int r=0;r<MI;++r) async16(gA + r*rnd + ko, As[cur^1] + r*2048 + t*8);
      #pragma unroll
      for (int r=0;r<4;++r)  async16(gB + r*rnd + ko, Bs[cur^1] + r*2048 + t*8);
    }
    const u16* as = As[cur];
    const u16* bs = Bs[cur];
    #pragma unroll
    for (int kk=0;kk<2;++kk){
      int so = (((kk*4+lq)^sw8))<<3;
      short8 a[MI], b[4];
      #pragma unroll
      for (int i=0;i<MI;++i) a[i] = *(const short8*)(as + (wm+i*16+lr)*64 + so);
      #pragma unroll
      for (int j=0;j<4;++j)  b[j] = *(const short8*)(bs + (wn+j*16+lr)*64 + so);
      #pragma unroll
      for (int i=0;i<MI;++i)
        #pragma unroll
        for (int j=0;j<4;++j)
          acc[i][j] = __builtin_amdgcn_mfma_f32_16x16x32_bf16(a[i], b[j], acc[i][j], 0,0,0);
    }
  }

  #pragma unroll
  for (int i=0;i<MI;++i){
    #pragma unroll
    for (int j=0;j<4;++j){
      int col = col0 + wn + j*16 + lr;
      float bv = bias ? bias[col] : 0.0f;
      #pragma unroll
      for (int r=0;r<4;++r){
        int row = row0 + wm + i*16 + lq*4 + r;
        float v = acc[i][j][r] + bv;
        if (do_relu) v = fmaxf(v, 0.0f);
        if (residual) v += b2f(residual[(size_t)row*N + col]);
        if (Cf) Cf[(size_t)row*N + col] = v;
        else    C [(size_t)row*N + col] = f2b(v);
      }
    }
  }
}

// ---------------- bf16 GEMM 256x256 tile, 8 waves, 4-phase/K-tile ----------------
// v3: staging consolidated — ALL 8 global_load_lds for tile k+1 issue at ph0 of
// tile k (issue order a0,a1,b0,b1,b2,b3,a2,a3).  Minimum load->wait cover rises
// from 2 phases (v1: B1' issued ph2, waited next ph0) to 3.5-5.5 phases (~HBM
// latency class).  FIFO ledger (per-thread): entry invariant = 4 outstanding
// {b2,b3,a2,a3 of cur}; ph0 +8 -> vmcnt(10) retires b2,b3 (ph1 reads);
// ph1 vmcnt(8) retires a2,a3 (ph2 reads); ph2 none; ph3 vmcnt(4) retires
// a0',a1',b0',b1' (next ph0 reads) -> invariant restored.  Buffer overwrite
// safe: tile k+1's buffer last read at ph3 of k-1, sealed by that barrier.
// Reads/MMQ/epilogue identical to the twice-passed v1.
__global__ __launch_bounds__(512,2) void gemm256(const u16* __restrict__ A, const u16* __restrict__ Bt,
    u16* __restrict__ C, float* __restrict__ Cf, int N, int K,
    const float* __restrict__ bias, const u16* __restrict__ residual, int do_relu, int gx)
{
  __shared__ __align__(16) u16 As[2][256*64];
  __shared__ __align__(16) u16 Bs[2][256*64];
  int t = threadIdx.x;
  int bid = blockIdx.y*gridDim.x + blockIdx.x;
  int xcd = bid & 7, slot = bid >> 3;
  int gy = 8/gx;
  int rx = gridDim.x/gx, ry = gridDim.y/gy;
  int col_b = (xcd%gx)*rx + slot%rx;
  int row_b = (xcd/gx)*ry + slot/rx;
  int row0 = row_b*256, col0 = col_b*256;
  int l = t&63, w = t>>6;
  int wr = w>>2, wc = w&3;           // 2 x 4 wave grid, per-wave 128(M) x 64(N)
  int lr = l&15, lq = l>>4, sw = lr&7;

  f32x4 acc[8][4];
  #pragma unroll
  for (int m=0;m<8;++m)
    #pragma unroll
    for (int n=0;n<4;++n) acc[m][n] = f32x4{0.f,0.f,0.f,0.f};

  int i = t>>3, c8 = t&7;
  int swc = (c8 ^ (i&7))*8;
  const u16* aS[4]; const u16* bS[4];
  {
    int la[4] = { i, 128+i, 64+i, 192+i };
    #pragma unroll
    for (int s=0;s<4;++s){
      aS[s] = A + (size_t)(row0 + la[s])*K + swc;
      int p = s*64 + i;
      int lb = ((p>>5)&3)*64 + (p>>7)*32 + (p&31);
      bS[s] = Bt + (size_t)(col0 + lb)*K + swc;
    }
  }
  int nk = K>>6;

  // prologue: stage tile 0 (order a0,a1,b0,b1,b2,b3,a2,a3); vmcnt(4) retires a0..b1
  async16(aS[0], As[0] + 0*4096 + t*8);
  async16(aS[1], As[0] + 1*4096 + t*8);
  async16(bS[0], Bs[0] + 0*4096 + t*8);
  async16(bS[1], Bs[0] + 1*4096 + t*8);
  async16(bS[2], Bs[0] + 2*4096 + t*8);
  async16(bS[3], Bs[0] + 3*4096 + t*8);
  async16(aS[2], As[0] + 2*4096 + t*8);
  async16(aS[3], As[0] + 3*4096 + t*8);
  asm volatile("s_waitcnt vmcnt(4)" ::: "memory");
  __builtin_amdgcn_s_barrier();

  short8 af[4][2], bf[2][2];

#define RD_A(qm) \
  _Pragma("unroll") \
  for (int mm=0;mm<4;++mm){ \
    _Pragma("unroll") \
    for (int kk=0;kk<2;++kk) \
      af[mm][kk] = *(const short8*)(asC + ((qm)*128 + wr*64 + mm*16 + lr)*64 + (((kk*4+lq)^sw)<<3)); \
  }
#define RD_B(qn) \
  _Pragma("unroll") \
  for (int nn=0;nn<2;++nn){ \
    _Pragma("unroll") \
    for (int kk=0;kk<2;++kk) \
      bf[nn][kk] = *(const short8*)(bsC + ((qn)*128 + wc*32 + nn*16 + lr)*64 + (((kk*4+lq)^sw)<<3)); \
  }
#define MMQ(qm,qn) \
  __builtin_amdgcn_s_setprio(1); \
  _Pragma("unroll") \
  for (int mm=0;mm<4;++mm){ \
    _Pragma("unroll") \
    for (int nn=0;nn<2;++nn){ \
      _Pragma("unroll") \
      for (int kk=0;kk<2;++kk) \
        acc[(qm)*4+mm][(qn)*2+nn] = __builtin_amdgcn_mfma_f32_16x16x32_bf16(af[mm][kk], bf[nn][kk], acc[(qm)*4+mm][(qn)*2+nn], 0,0,0); \
    } \
  } \
  __builtin_amdgcn_s_setprio(0);
#define BARW \
  __builtin_amdgcn_s_barrier(); \
  asm volatile("s_waitcnt lgkmcnt(0)" ::: "memory"); \
  __builtin_amdgcn_sched_barrier(0);
#define PIN __builtin_amdgcn_sched_barrier(0);

  for (int kt=0; kt<nk-1; ++kt){
    int cur = kt&1;
    const u16* asC = As[cur]; const u16* bsC = Bs[cur];
    u16* asN = As[cur^1];    u16* bsN = Bs[cur^1];
    int ko = (kt+1)<<6;
    // ph0: quadrant (0,0); issue ALL 8 loads for tile kt+1; retire b2,b3 of cur
    RD_A(0); RD_B(0);
    async16(aS[0]+ko, asN + 0*4096 + t*8);
    async16(aS[1]+ko, asN + 1*4096 + t*8);
    async16(bS[0]+ko, bsN + 0*4096 + t*8);
    async16(bS[1]+ko, bsN + 1*4096 + t*8);
    async16(bS[2]+ko, bsN + 2*4096 + t*8);
    async16(bS[3]+ko, bsN + 3*4096 + t*8);
    async16(aS[2]+ko, asN + 2*4096 + t*8);
    async16(aS[3]+ko, asN + 3*4096 + t*8);
    PIN;
    asm volatile("s_waitcnt vmcnt(10)" ::: "memory");
    BARW;
    MMQ(0,0);
    __builtin_amdgcn_s_barrier();
    // ph1: quadrant (0,1), reuse af; retire a2,a3 of cur
    RD_B(1);
    PIN;
    asm volatile("s_waitcnt vmcnt(8)" ::: "memory");
    BARW;
    MMQ(0,1);
    __builtin_amdgcn_s_barrier();
    // ph2: quadrant (1,1), reuse bf; no wait
    RD_A(1);
    PIN;
    BARW;
    MMQ(1,1);
    __builtin_amdgcn_s_barrier();
    // ph3: quadrant (1,0); retire a0',a1',b0',b1' (next ph0 reads)
    RD_B(0);
    PIN;
    asm volatile("s_waitcnt vmcnt(4)" ::: "memory");
    BARW;
    MMQ(1,0);
    __builtin_amdgcn_s_barrier();
  }
  { // last tile: no staging; entry outstanding = {b2,b3,a2,a3} of last
    int cur = (nk-1)&1;
    const u16* asC = As[cur]; const u16* bsC = Bs[cur];
    RD_A(0); RD_B(0);
    asm volatile("s_waitcnt vmcnt(2)" ::: "memory");
    BARW;
    MMQ(0,0);
    __builtin_amdgcn_s_barrier();
    RD_B(1);
    asm volatile("s_waitcnt vmcnt(0)" ::: "memory");
    BARW;
    MMQ(0,1);
    __builtin_amdgcn_s_barrier();
    RD_A(1);
    BARW;
    MMQ(1,1);
    __builtin_amdgcn_s_barrier();
    RD_B(0);
    BARW;
    MMQ(1,0);
  }
#undef RD_A
#undef RD_B
#undef MMQ
#undef BARW
#undef PIN

  #pragma unroll
  for (int m=0;m<8;++m){
    #pragma unroll
    for (int n=0;n<4;++n){
      int col = col0 + wc*64 + n*16 + lr;
      float bv = bias ? bias[col] : 0.0f;
      #pragma unroll
      for (int r=0;r<4;++r){
        int row = row0 + wr*128 + m*16 + lq*4 + r;
        float v = acc[m][n][r] + bv;
        if (do_relu) v = fmaxf(v, 0.0f);
        if (residual) v += b2f(residual[(size_t)row*N + col]);
        if (Cf) Cf[(size_t)row*N + col] = v;
        else    C [(size_t)row*N + col] = f2b(v);
      }
    }
  }
}

// ---------------- causal flash attention v4 ----------------
// Q-tile 64 (4 waves x 16 q rows), s-tile 64 double-buffered, grid 1024.
// S^T via K=32 mfma; P stays IN-LANE (C-layout == K=16 A-layout), PV via
// 16x16x16 mfma on packed bf16 — no P LDS round-trip. Complementary-qt
// slot pairing balances per-CU work. K and V^T staged via global_load_lds.
__global__ __launch_bounds__(256,4) void attn_kernel(const u16* __restrict__ QKV,
    const u16* __restrict__ VT, u16* __restrict__ O)
{
  const int T=2048, LD=3072, E=1024;
  int bid = blockIdx.y * gridDim.x + blockIdx.x;
  int xcd = bid & 7, slot = bid >> 3;
  int idx = slot & 31, grp = slot >> 5;
  int qt = (grp & 1) ? idx : 31 - idx;   // heavy-first, complementary pairing
  int bh = xcd*4 + grp;
  int bb = bh>>4, h = bh&15;
  const u16* base = QKV + (size_t)bb*T*LD;
  const u16* Qp = base + h*64;
  const u16* Kp = base + 1024 + h*64;
  const u16* Vtp = VT + (size_t)bh*64*2048;
  int t = threadIdx.x, l = t&63, w = t>>6;
  int lr = l&15, lq = l>>4;

  __shared__ __align__(16) u16 Ks[2][64*64];   // [s][d], chunk c at slot c^(s&7)
  __shared__ __align__(16) u16 Vs[2][64*64];   // [d][s], chunk c at slot c^(d&7)

  const float QSC = 0.125f*1.44269504f;
  int q0 = qt*64 + w*16;
  short8 aq[2];
  #pragma unroll
  for (int kk=0;kk<2;++kk){
    short8 raw = *(const short8*)(Qp + (size_t)(q0+lr)*LD + kk*32 + lq*8);
    short8 sc;
    #pragma unroll
    for (int j=0;j<8;++j) sc[j] = (short)f2b(b2f((u16)raw[j])*QSC);
    aq[kk]=sc;
  }

  float mrun = -3e38f, lrun = 0.f;
  f32x4 Oacc[4];
  #pragma unroll
  for (int dt=0;dt<4;++dt) Oacc[dt] = f32x4{0.f,0.f,0.f,0.f};

  int kc = (l&7) ^ (l>>3);
  int ra = 8*w + (l>>3);

  // prologue: stage tile 0
  async16(Kp  + (size_t)ra*LD        + kc*8, Ks[0] + t*8);
  async16(Kp  + (size_t)(ra+32)*LD   + kc*8, Ks[0] + 2048 + t*8);
  async16(Vtp + (size_t)ra*2048      + kc*8, Vs[0] + t*8);
  async16(Vtp + (size_t)(ra+32)*2048 + kc*8, Vs[0] + 2048 + t*8);

  for (int it=0; it<=qt; ++it){
    int s0 = it*64, cur = it&1;
    __syncthreads();
    if (it < qt){
      int sn = s0+64;
      u16* kd = Ks[cur^1]; u16* vd = Vs[cur^1];
      async16(Kp  + (size_t)(sn+ra)*LD        + kc*8, kd + t*8);
      async16(Kp  + (size_t)(sn+ra+32)*LD     + kc*8, kd + 2048 + t*8);
      async16(Vtp + (size_t)ra*2048      + sn + kc*8, vd + t*8);
      async16(Vtp + (size_t)(ra+32)*2048 + sn + kc*8, vd + 2048 + t*8);
    }
    const u16* ks = Ks[cur];
    const u16* vs = Vs[cur];

    // S^T[s][q] for this wave's 16 q
    f32x4 S[4];
    #pragma unroll
    for (int st=0; st<4; ++st){
      short8 kf0 = *(const short8*)(ks + (st*16+lr)*64 + ((lq  )^(lr&7))*8);
      short8 kf1 = *(const short8*)(ks + (st*16+lr)*64 + ((4+lq)^(lr&7))*8);
      f32x4 z = f32x4{0.f,0.f,0.f,0.f};
      z = __builtin_amdgcn_mfma_f32_16x16x32_bf16(kf0, aq[0], z, 0,0,0);
      z = __builtin_amdgcn_mfma_f32_16x16x32_bf16(kf1, aq[1], z, 0,0,0);
      S[st] = z;
    }
    if (it == qt){
      int qg = q0 + lr;
      #pragma unroll
      for (int st=0;st<4;++st)
        #pragma unroll
        for (int r=0;r<4;++r){
          int sg = s0 + st*16 + lq*4 + r;
          if (sg > qg) S[st][r] = -3e38f;
        }
    }
    // online softmax (q = lr; s-reduction in-lane + 2 shuffles)
    float m = S[0][0];
    #pragma unroll
    for (int st=0;st<4;++st)
      #pragma unroll
      for (int r=0;r<4;++r) m = fmaxf(m, S[st][r]);
    m = fmaxf(m, __shfl_xor(m,16));
    m = fmaxf(m, __shfl_xor(m,32));
    float mnew = fmaxf(mrun, m);
    float alpha = EXP2F(mrun - mnew);
    mrun = mnew;
    float ssum = 0.f;
    #pragma unroll
    for (int st=0;st<4;++st)
      #pragma unroll
      for (int r=0;r<4;++r){ float p = EXP2F(S[st][r]-mnew); S[st][r]=p; ssum+=p; }
    ssum += __shfl_xor(ssum,16);
    ssum += __shfl_xor(ssum,32);
    lrun = lrun*alpha + ssum;
    // P: in-lane pack to K=16 A-fragments
    short4_t pk[4];
    #pragma unroll
    for (int st=0;st<4;++st) pk[st] = pack4(S[st]);
    // rescale O (O rows: q = lq*4+r)
    float af[4];
    #pragma unroll
    for (int r=0;r<4;++r) af[r] = __shfl(alpha, lq*4+r);
    #pragma unroll
    for (int dt=0;dt<4;++dt)
      #pragma unroll
      for (int r=0;r<4;++r) Oacc[dt][r] *= af[r];
    // PV: 16 x mfma_16x16x16
    #pragma unroll
    for (int st=0;st<4;++st){
      #pragma unroll
      for (int dt=0;dt<4;++dt){
        short4_t vf = *(const short4_t*)(vs + (dt*16+lr)*64 + ((2*st+(lq>>1))^(lr&7))*8 + (lq&1)*4);
        Oacc[dt] = MFMA16(pk[st], vf, Oacc[dt]);
      }
    }
  }
  float linv[4];
  #pragma unroll
  for (int r=0;r<4;++r) linv[r] = 1.0f/__shfl(lrun, lq*4+r);
  #pragma unroll
  for (int dt=0;dt<4;++dt)
    #pragma unroll
    for (int r=0;r<4;++r){
      int qg = q0 + lq*4 + r;
      O[(size_t)(bb*T+qg)*E + h*64 + dt*16 + lr] = f2b(Oacc[dt][r]*linv[r]);
    }
}

// ---------------- host ----------------
extern "C" void kernel_launch(void* const* d_in, const int* in_sizes, int n_in,
                              void* d_out, int out_size, void* d_ws, size_t ws_size,
                              hipStream_t stream)
{
  (void)in_sizes; (void)n_in; (void)out_size; (void)ws_size;
  const float* x     = (const float*)d_in[0];
  const float* wq    = (const float*)d_in[1];
  const float* wk    = (const float*)d_in[2];
  const float* wv    = (const float*)d_in[3];
  const float* wproj = (const float*)d_in[4];
  const float* bproj = (const float*)d_in[5];
  const float* g1    = (const float*)d_in[6];
  const float* be1   = (const float*)d_in[7];
  const float* g2    = (const float*)d_in[8];
  const float* be2   = (const float*)d_in[9];
  const float* w1    = (const float*)d_in[10];
  const float* b1    = (const float*)d_in[11];
  const float* w2    = (const float*)d_in[12];
  const float* b2    = (const float*)d_in[13];
  float* out = (float*)d_out;

  char* ws = (char*)d_ws;
  size_t off = 0;
  auto alloc = [&](size_t bytes)->void*{ void* p = ws + off; off += (bytes + 255) & ~(size_t)255; return p; };
  u16* hnorm  = (u16*)alloc((size_t)4096*1024*2);
  u16* qkv    = (u16*)alloc((size_t)4096*3072*2);
  u16* VT     = (u16*)alloc((size_t)32*64*2048*2);
  u16* attnO  = (u16*)alloc((size_t)4096*1024*2);
  u16* x2     = (u16*)alloc((size_t)4096*1024*2);
  u16* h2     = (u16*)alloc((size_t)4096*1024*2);
  u16* ffn1   = (u16*)alloc((size_t)4096*4096*2);
  u16* wqkvT  = (u16*)alloc((size_t)3072*1024*2);
  u16* wprojT = (u16*)alloc((size_t)1024*1024*2);
  u16* w1T    = (u16*)alloc((size_t)4096*1024*2);
  u16* w2T    = (u16*)alloc((size_t)1024*4096*2);

  qkv_repack  <<<dim3(16,48),256,0,stream>>>(wq,wk,wv,wqkvT);
  transpose_bt<<<dim3(16,16),256,0,stream>>>(wproj, wprojT, 1024, 1024);
  transpose_bt<<<dim3(64,16),256,0,stream>>>(w1,    w1T,    4096, 1024);
  transpose_bt<<<dim3(16,64),256,0,stream>>>(w2,    w2T,    1024, 4096);

  ln_kernel<1><<<4096,256,0,stream>>>(x, g1, be1, hnorm);
  gemm256<<<dim3(12,16),512,0,stream>>>(hnorm, wqkvT, qkv, nullptr, 3072, 1024, nullptr, nullptr, 0, 4);
  vtrans<<<dim3(32,32),256,0,stream>>>(qkv, VT);
  attn_kernel<<<dim3(32,32),256,0,stream>>>(qkv, VT, attnO);
  gemm_bt<2><<<dim3(8,64),256,0,stream>>>(attnO, wprojT, x2, nullptr, 4096,1024,1024, bproj, hnorm, 0, 2);
  ln_kernel<0><<<4096,256,0,stream>>>(x2, g2, be2, h2);
  gemm256<<<dim3(16,16),512,0,stream>>>(h2, w1T, ffn1, nullptr, 4096, 1024, b1, nullptr, 1, 4);
  gemm_bt<2><<<dim3(8,64),256,0,stream>>>(ffn1, w2T, nullptr, out, 4096,1024,4096, b2, h2, 0, 2);
}

// Round 8
// 358.539 us; speedup vs baseline: 1.0986x; 1.0076x over previous
//
#include <hip/hip_runtime.h>
#include <stdint.h>

typedef unsigned short u16;
typedef __attribute__((ext_vector_type(8))) short short8;
typedef __attribute__((ext_vector_type(4))) short short4_t;
typedef __attribute__((ext_vector_type(4))) float f32x4;

__device__ __forceinline__ float b2f(u16 u){ union{unsigned i; float f;}v; v.i=((unsigned)u)<<16; return v.f; }
__device__ __forceinline__ u16 f2b(float f){ unsigned x=__float_as_uint(f); return (u16)((x + 0x7fffu + ((x>>16)&1u))>>16); }

#if __has_builtin(__builtin_amdgcn_exp2f)
#define EXP2F(x) __builtin_amdgcn_exp2f(x)
#else
#define EXP2F(x) exp2f(x)
#endif

#if __has_builtin(__builtin_amdgcn_mfma_f32_16x16x16_bf16)
#define MFMA16(a,b,c) __builtin_amdgcn_mfma_f32_16x16x16_bf16(a,b,c,0,0,0)
#elif __has_builtin(__builtin_amdgcn_mfma_f32_16x16x16bf16_1k)
#define MFMA16(a,b,c) __builtin_amdgcn_mfma_f32_16x16x16bf16_1k(a,b,c,0,0,0)
#else
static __device__ __forceinline__ f32x4 mfma16_asm(short4_t a, short4_t b, f32x4 c){
  __asm__("v_mfma_f32_16x16x16_bf16 %0, %1, %2, %3" : "=v"(c) : "v"(a), "v"(b), "0"(c));
  return c;
}
#define MFMA16(a,b,c) mfma16_asm(a,b,c)
#endif

__device__ __forceinline__ void async16(const void* g, void* l){
  __builtin_amdgcn_global_load_lds((const __attribute__((address_space(1))) void*)g,
                                   (__attribute__((address_space(3))) void*)l, 16, 0, 0);
}

// pack 4 fp32 (in [0,1]) -> 4 bf16 (round-half-up) as K=16 A-fragment regs
__device__ __forceinline__ short4_t pack4(f32x4 s){
  unsigned u0 = (__float_as_uint(s[0]) + 0x8000u) >> 16;
  unsigned u1 = (__float_as_uint(s[1]) + 0x8000u) & 0xffff0000u;
  unsigned u2 = (__float_as_uint(s[2]) + 0x8000u) >> 16;
  unsigned u3 = (__float_as_uint(s[3]) + 0x8000u) & 0xffff0000u;
  union { unsigned v[2]; short4_t s4; } r;
  r.v[0] = u0 | u1; r.v[1] = u2 | u3;
  return r.s4;
}

// ---------------- LayerNorm (E=1024, one block per row) ----------------
template<int IN_F32>
__global__ __launch_bounds__(256) void ln_kernel(const void* __restrict__ xin,
    const float* __restrict__ g, const float* __restrict__ b, u16* __restrict__ y)
{
  const int E = 1024;
  int row = blockIdx.x, t = threadIdx.x;
  float f0,f1,f2,f3;
  if (IN_F32){
    const float* xr = (const float*)xin + (size_t)row*E;
    float4 xv = *(const float4*)(xr + t*4);
    f0=xv.x; f1=xv.y; f2=xv.z; f3=xv.w;
  } else {
    const u16* xr = (const u16*)xin + (size_t)row*E;
    ushort4 xv = *(const ushort4*)(xr + t*4);
    f0=b2f(xv.x); f1=b2f(xv.y); f2=b2f(xv.z); f3=b2f(xv.w);
  }
  float s1 = f0+f1+f2+f3;
  float s2 = f0*f0+f1*f1+f2*f2+f3*f3;
  #pragma unroll
  for (int off=32; off>=1; off>>=1){ s1 += __shfl_xor(s1,off); s2 += __shfl_xor(s2,off); }
  __shared__ float red[8];
  int w = t>>6;
  if ((t&63)==0){ red[w]=s1; red[4+w]=s2; }
  __syncthreads();
  float S1 = red[0]+red[1]+red[2]+red[3];
  float S2 = red[4]+red[5]+red[6]+red[7];
  float mean = S1*(1.0f/E);
  float var  = S2*(1.0f/E) - mean*mean;
  float inv  = rsqrtf(var + 1e-5f);
  float4 gv = *(const float4*)(g + t*4);
  float4 bv = *(const float4*)(b + t*4);
  ushort4 o;
  o.x = f2b((f0-mean)*inv*gv.x+bv.x);
  o.y = f2b((f1-mean)*inv*gv.y+bv.y);
  o.z = f2b((f2-mean)*inv*gv.z+bv.z);
  o.w = f2b((f3-mean)*inv*gv.w+bv.w);
  *(ushort4*)(y + (size_t)row*E + t*4) = o;
}

// ---------------- fp32->bf16 64x64-tiled transpose ----------------
__global__ __launch_bounds__(256) void transpose_bt(const float* __restrict__ src, u16* __restrict__ dst,
                                                    int ld_src, int ld_dst)
{
  __shared__ u16 tile[64*66];
  int c0 = blockIdx.x*64, r0 = blockIdx.y*64;
  int t = threadIdx.x;
  #pragma unroll
  for (int i=0;i<16;++i){
    int lin = i*256 + t;
    int rr = lin>>6, cc = lin&63;
    tile[cc*66+rr] = f2b(src[(size_t)(r0+rr)*ld_src + c0+cc]);
  }
  __syncthreads();
  #pragma unroll
  for (int i=0;i<16;++i){
    int lin = i*256 + t;
    int cc = lin>>6, rr = lin&63;
    dst[(size_t)(c0+cc)*ld_dst + r0+rr] = tile[cc*66+rr];
  }
}

// ---------------- QKV weight repack ----------------
__global__ __launch_bounds__(256) void qkv_repack(const float* __restrict__ wq, const float* __restrict__ wk,
                                                  const float* __restrict__ wv, u16* __restrict__ dst)
{
  __shared__ u16 tile[64*66];
  int e0 = blockIdx.x*64;
  int sel = blockIdx.y>>4, h = blockIdx.y&15;
  const float* src = (sel==0?wq:(sel==1?wk:wv)) + (size_t)h*1024*64;
  int t = threadIdx.x;
  #pragma unroll
  for (int i=0;i<16;++i){
    int lin=i*256+t; int rr=lin>>6, cc=lin&63;
    tile[cc*66+rr] = f2b(src[(size_t)(e0+rr)*64 + cc]);
  }
  __syncthreads();
  #pragma unroll
  for (int i=0;i<16;++i){
    int lin=i*256+t; int cc=lin>>6, rr=lin&63;
    dst[(size_t)(sel*1024 + h*64 + cc)*1024 + e0+rr] = tile[cc*66+rr];
  }
}

// ---------------- V transpose: qkv V-slice -> VT[bh][64][2048] ----------------
__global__ __launch_bounds__(256) void vtrans(const u16* __restrict__ qkv, u16* __restrict__ VT)
{
  __shared__ u16 tile[64*66];
  int bh = blockIdx.y, bb = bh>>4, h = bh&15;
  int s0 = blockIdx.x*64;
  const u16* src = qkv + ((size_t)(bb*2048) + s0)*3072 + 2048 + h*64;
  int t = threadIdx.x;
  int sr = t>>3, c0 = (t&7)*8;
  #pragma unroll
  for (int half=0; half<2; ++half){
    const u16* p = src + (size_t)(sr+half*32)*3072 + c0;
    ushort4 v0 = *(const ushort4*)p;
    ushort4 v1 = *(const ushort4*)(p+4);
    uint* d = (uint*)(tile + (sr+half*32)*66 + c0);
    d[0] = (uint)v0.x | ((uint)v0.y<<16);
    d[1] = (uint)v0.z | ((uint)v0.w<<16);
    d[2] = (uint)v1.x | ((uint)v1.y<<16);
    d[3] = (uint)v1.z | ((uint)v1.w<<16);
  }
  __syncthreads();
  u16* out = VT + (size_t)bh*64*2048 + s0;
  int dw = t>>3, sc = (t&7)*8;
  #pragma unroll
  for (int half=0; half<2; ++half){
    int d = dw + half*32;
    short8 pk;
    #pragma unroll
    for (int j=0;j<8;++j) pk[j] = (short)tile[(sc+j)*66 + d];
    *(short8*)(out + (size_t)d*2048 + sc) = pk;
  }
}

// ---------------- bf16 GEMM: C[M][N] = A[M][K] * Bt[N][K]^T (legacy 2-phase) ----------------
template<int MI>
__global__ __launch_bounds__(256, 3) void gemm_bt(const u16* __restrict__ A, const u16* __restrict__ Bt,
    u16* __restrict__ C, float* __restrict__ Cf, int M, int N, int K,
    const float* __restrict__ bias, const u16* __restrict__ residual, int do_relu, int gx)
{
  __shared__ __align__(16) u16 As[2][MI*32*64];
  __shared__ __align__(16) u16 Bs[2][128*64];
  int t = threadIdx.x;
  int bid = blockIdx.y * gridDim.x + blockIdx.x;
  int xcd = bid & 7, slot = bid >> 3;
  int gy = 8 / gx;
  int rx = gridDim.x / gx, ry = gridDim.y / gy;
  int col_b = (xcd % gx) * rx + (slot % rx);
  int row_b = (xcd / gx) * ry + (slot / rx);
  int row0 = row_b*(MI*32), col0 = col_b*128;
  int l = t&63, w = t>>6;
  int wm = (w>>1)*(MI*16), wn = (w&1)*64;
  int lr = l&15, lq = l>>4;
  (void)M;

  f32x4 acc[MI][4];
  #pragma unroll
  for (int i=0;i<MI;++i)
    #pragma unroll
    for (int j=0;j<4;++j) acc[i][j] = f32x4{0.f,0.f,0.f,0.f};

  const u16* gA = A  + (size_t)(row0 + (t>>3))*K + (((t&7)^((t>>3)&7))<<3);
  const u16* gB = Bt + (size_t)(col0 + (t>>3))*K + (((t&7)^((t>>3)&7))<<3);
  const size_t rnd = (size_t)32*K;
  int nk = K>>6;

  #pragma unroll
  for (int r=0;r<MI;++r) async16(gA + r*rnd, As[0] + r*2048 + t*8);
  #pragma unroll
  for (int r=0;r<4;++r)  async16(gB + r*rnd, Bs[0] + r*2048 + t*8);

  int sw8 = (lr&7);
  for (int kt=0; kt<nk; ++kt){
    int cur = kt&1;
    __syncthreads();
    if (kt+1 < nk){
      int ko = (kt+1)<<6;
      #pragma unroll
      for (int r=0;r<MI;++r) async16(gA + r*rnd + ko, As[cur^1] + r*2048 + t*8);
      #pragma unroll
      for (int r=0;r<4;++r)  async16(gB + r*rnd + ko, Bs[cur^1] + r*2048 + t*8);
    }
    const u16* as = As[cur];
    const u16* bs = Bs[cur];
    #pragma unroll
    for (int kk=0;kk<2;++kk){
      int so = (((kk*4+lq)^sw8))<<3;
      short8 a[MI], b[4];
      #pragma unroll
      for (int i=0;i<MI;++i) a[i] = *(const short8*)(as + (wm+i*16+lr)*64 + so);
      #pragma unroll
      for (int j=0;j<4;++j)  b[j] = *(const short8*)(bs + (wn+j*16+lr)*64 + so);
      #pragma unroll
      for (int i=0;i<MI;++i)
        #pragma unroll
        for (int j=0;j<4;++j)
          acc[i][j] = __builtin_amdgcn_mfma_f32_16x16x32_bf16(a[i], b[j], acc[i][j], 0,0,0);
    }
  }

  #pragma unroll
  for (int i=0;i<MI;++i){
    #pragma unroll
    for (int j=0;j<4;++j){
      int col = col0 + wn + j*16 + lr;
      float bv = bias ? bias[col] : 0.0f;
      #pragma unroll
      for (int r=0;r<4;++r){
        int row = row0 + wm + i*16 + lq*4 + r;
        float v = acc[i][j][r] + bv;
        if (do_relu) v = fmaxf(v, 0.0f);
        if (residual) v += b2f(residual[(size_t)row*N + col]);
        if (Cf) Cf[(size_t)row*N + col] = v;
        else    C [(size_t)row*N + col] = f2b(v);
      }
    }
  }
}

// ---------------- bf16 GEMM 256x256 tile, 8 waves, 4-phase/K-tile ----------------
// v4: m201-style wait discipline.  Stage 1 half-tile (2 loads) per phase:
//   p_a: A1(k+1)->buf[cur^1];  p_b: B1(k+2)->buf[cur];  p_c: A0(k+2)->buf[cur];
//   p_d: B0(k+2)->buf[cur]    (each lands >=1 barrier after its slot's last read)
// Waits: ONLY vmcnt(8) at p_b and p_d (2 stall points/K-tile vs v1/v3's 3);
// p_a and p_c have none.  Steady-state outstanding = 4 halves
// {A1(k+1),B1(k+2),A0(k+2),B0(k+2)}; every ds_read's data is >=4 phases old and
// retired by the VM+BAR pair preceding it (cross-wave safe).  Fragment reads
// after MFMA (v2 style), fixed register roles af/bP/bQ (no per-tile swap).
// Prologue: 14 loads {A0,B0,B1,A1}(0)+{A0,B0,B1}(1), vmcnt(8).  kt=nk-2 clamps
// ko2 -> duplicate stages into dead slots (uniform counts).  Tail: stage-less,
// vmcnt(6)@p_b.  vmcnt(0) before epilogue drains async LDS writes.
__global__ __launch_bounds__(512,2) void gemm256(const u16* __restrict__ A, const u16* __restrict__ Bt,
    u16* __restrict__ C, float* __restrict__ Cf, int N, int K,
    const float* __restrict__ bias, const u16* __restrict__ residual, int do_relu, int gx)
{
  __shared__ __align__(16) u16 As[2][256*64];
  __shared__ __align__(16) u16 Bs[2][256*64];
  int t = threadIdx.x;
  int bid = blockIdx.y*gridDim.x + blockIdx.x;
  int xcd = bid & 7, slot = bid >> 3;
  int gy = 8/gx;
  int rx = gridDim.x/gx, ry = gridDim.y/gy;
  int col_b = (xcd%gx)*rx + slot%rx;
  int row_b = (xcd/gx)*ry + slot/rx;
  int row0 = row_b*256, col0 = col_b*256;
  int l = t&63, w = t>>6;
  int wr = w>>2, wc = w&3;           // 2 x 4 wave grid, per-wave 128(M) x 64(N)
  int lr = l&15, lq = l>>4, sw = lr&7;

  f32x4 acc[8][4];
  #pragma unroll
  for (int m=0;m<8;++m)
    #pragma unroll
    for (int n=0;n<4;++n) acc[m][n] = f32x4{0.f,0.f,0.f,0.f};

  int i = t>>3, c8 = t&7;
  int swc = (c8 ^ (i&7))*8;
  const u16* aS[4]; const u16* bS[4];
  {
    int la[4] = { i, 128+i, 64+i, 192+i };
    #pragma unroll
    for (int s=0;s<4;++s){
      aS[s] = A + (size_t)(row0 + la[s])*K + swc;
      int p = s*64 + i;
      int lb = ((p>>5)&3)*64 + (p>>7)*32 + (p&31);
      bS[s] = Bt + (size_t)(col0 + lb)*K + swc;
    }
  }
  int nk = K>>6;   // requires nk >= 3

  u16* A0p = As[0]; u16* A1p = As[1];
  u16* B0p = Bs[0]; u16* B1p = Bs[1];

  short8 af[4][2], bP[2][2], bQ[2][2];

#define VM8  asm volatile("s_waitcnt vmcnt(8)" ::: "memory");
#define VM6  asm volatile("s_waitcnt vmcnt(6)" ::: "memory");
#define VM0  asm volatile("s_waitcnt vmcnt(0)" ::: "memory");
#define LGK  asm volatile("s_waitcnt lgkmcnt(0)" ::: "memory");
#define BAR  __builtin_amdgcn_s_barrier();
#define PIN  __builtin_amdgcn_sched_barrier(0);

#define RD_A(BUF,qm) \
  _Pragma("unroll") \
  for (int mm=0;mm<4;++mm){ \
    _Pragma("unroll") \
    for (int kk=0;kk<2;++kk) \
      af[mm][kk] = *(const short8*)((const u16*)(BUF) + ((qm)*128 + wr*64 + mm*16 + lr)*64 + (((kk*4+lq)^sw)<<3)); \
  }
#define RD_B(DST,BUF,qn) \
  _Pragma("unroll") \
  for (int nn=0;nn<2;++nn){ \
    _Pragma("unroll") \
    for (int kk=0;kk<2;++kk) \
      DST[nn][kk] = *(const short8*)((const u16*)(BUF) + ((qn)*128 + wc*32 + nn*16 + lr)*64 + (((kk*4+lq)^sw)<<3)); \
  }
#define MMQ(qm,qn,BSS) \
  __builtin_amdgcn_s_setprio(1); \
  _Pragma("unroll") \
  for (int mm=0;mm<4;++mm){ \
    _Pragma("unroll") \
    for (int nn=0;nn<2;++nn){ \
      _Pragma("unroll") \
      for (int kk=0;kk<2;++kk) \
        acc[(qm)*4+mm][(qn)*2+nn] = __builtin_amdgcn_mfma_f32_16x16x32_bf16(af[mm][kk], BSS[nn][kk], acc[(qm)*4+mm][(qn)*2+nn], 0,0,0); \
    } \
  } \
  __builtin_amdgcn_s_setprio(0);

  // prologue: 14 loads — tile0 {A0,B0,B1,A1} -> buf0; tile1 {A0,B0,B1} -> buf1
  async16(aS[0], A0p + 0*4096 + t*8);
  async16(aS[1], A0p + 1*4096 + t*8);
  async16(bS[0], B0p + 0*4096 + t*8);
  async16(bS[1], B0p + 1*4096 + t*8);
  async16(bS[2], B0p + 2*4096 + t*8);
  async16(bS[3], B0p + 3*4096 + t*8);
  async16(aS[2], A0p + 2*4096 + t*8);
  async16(aS[3], A0p + 3*4096 + t*8);
  async16(aS[0]+64, A1p + 0*4096 + t*8);
  async16(aS[1]+64, A1p + 1*4096 + t*8);
  async16(bS[0]+64, B1p + 0*4096 + t*8);
  async16(bS[1]+64, B1p + 1*4096 + t*8);
  async16(bS[2]+64, B1p + 2*4096 + t*8);
  async16(bS[3]+64, B1p + 3*4096 + t*8);
  VM8; BAR;                               // retires tile0 {A0,B0,B1}
  RD_A(A0p, 0); RD_B(bP, B0p, 0); PIN;

  for (int kt=0; kt<nk-1; ++kt){
    int cur = kt&1;
    u16* Ac = As[cur]; u16* Bc = Bs[cur];
    u16* An = As[cur^1]; u16* Bn = Bs[cur^1];
    int ko1 = (kt+1)<<6;
    int kc2 = (kt+2 < nk) ? kt+2 : nk-1;
    int ko2 = kc2<<6;
    // p_a: MMQ(0,0); stage A1(k+1)->next buf
    async16(aS[2]+ko1, An + 2*4096 + t*8);
    async16(aS[3]+ko1, An + 3*4096 + t*8);
    PIN; BAR; LGK; PIN;
    MMQ(0,0,bP);
    RD_B(bQ, Bc, 1); PIN;
    BAR;
    // p_b: MMQ(0,1); stage B1(k+2)->cur buf; wait
    async16(bS[2]+ko2, Bc + 2*4096 + t*8);
    async16(bS[3]+ko2, Bc + 3*4096 + t*8);
    PIN; VM8; BAR; LGK; PIN;
    MMQ(0,1,bQ);
    RD_A(Ac, 1); PIN;
    BAR;
    // p_c: MMQ(1,1); stage A0(k+2)->cur buf
    async16(aS[0]+ko2, Ac + 0*4096 + t*8);
    async16(aS[1]+ko2, Ac + 1*4096 + t*8);
    PIN; BAR; LGK; PIN;
    MMQ(1,1,bQ);
    PIN; BAR;
    // p_d: MMQ(1,0); stage B0(k+2)->cur buf; wait; prefetch-read next A0,B0
    async16(bS[0]+ko2, Bc + 0*4096 + t*8);
    async16(bS[1]+ko2, Bc + 1*4096 + t*8);
    PIN; VM8; BAR; LGK; PIN;
    MMQ(1,0,bP);
    RD_A(An, 0); RD_B(bP, Bn, 0); PIN;
    BAR;
  }
  { // tail tile (nk-1): no staging
    int cur = (nk-1)&1;
    u16* Ac = As[cur]; u16* Bc = Bs[cur];
    BAR; LGK; PIN;
    MMQ(0,0,bP);
    RD_B(bQ, Bc, 1); PIN;
    BAR;
    VM6; BAR; LGK; PIN;                   // retires A1(nk-1)
    MMQ(0,1,bQ);
    RD_A(Ac, 1); PIN;
    LGK; PIN;
    MMQ(1,1,bQ);
    MMQ(1,0,bP);
  }
  VM0;   // drain remaining async LDS writes before reusing/ending

#undef VM8
#undef VM6
#undef VM0
#undef LGK
#undef BAR
#undef PIN
#undef RD_A
#undef RD_B
#undef MMQ

  #pragma unroll
  for (int m=0;m<8;++m){
    #pragma unroll
    for (int n=0;n<4;++n){
      int col = col0 + wc*64 + n*16 + lr;
      float bv = bias ? bias[col] : 0.0f;
      #pragma unroll
      for (int r=0;r<4;++r){
        int row = row0 + wr*128 + m*16 + lq*4 + r;
        float v = acc[m][n][r] + bv;
        if (do_relu) v = fmaxf(v, 0.0f);
        if (residual) v += b2f(residual[(size_t)row*N + col]);
        if (Cf) Cf[(size_t)row*N + col] = v;
        else    C [(size_t)row*N + col] = f2b(v);
      }
    }
  }
}

// ---------------- causal flash attention v4 ----------------
// Q-tile 64 (4 waves x 16 q rows), s-tile 64 double-buffered, grid 1024.
// S^T via K=32 mfma; P stays IN-LANE (C-layout == K=16 A-layout), PV via
// 16x16x16 mfma on packed bf16 — no P LDS round-trip. Complementary-qt
// slot pairing balances per-CU work. K and V^T staged via global_load_lds.
__global__ __launch_bounds__(256,4) void attn_kernel(const u16* __restrict__ QKV,
    const u16* __restrict__ VT, u16* __restrict__ O)
{
  const int T=2048, LD=3072, E=1024;
  int bid = blockIdx.y * gridDim.x + blockIdx.x;
  int xcd = bid & 7, slot = bid >> 3;
  int idx = slot & 31, grp = slot >> 5;
  int qt = (grp & 1) ? idx : 31 - idx;   // heavy-first, complementary pairing
  int bh = xcd*4 + grp;
  int bb = bh>>4, h = bh&15;
  const u16* base = QKV + (size_t)bb*T*LD;
  const u16* Qp = base + h*64;
  const u16* Kp = base + 1024 + h*64;
  const u16* Vtp = VT + (size_t)bh*64*2048;
  int t = threadIdx.x, l = t&63, w = t>>6;
  int lr = l&15, lq = l>>4;

  __shared__ __align__(16) u16 Ks[2][64*64];   // [s][d], chunk c at slot c^(s&7)
  __shared__ __align__(16) u16 Vs[2][64*64];   // [d][s], chunk c at slot c^(d&7)

  const float QSC = 0.125f*1.44269504f;
  int q0 = qt*64 + w*16;
  short8 aq[2];
  #pragma unroll
  for (int kk=0;kk<2;++kk){
    short8 raw = *(const short8*)(Qp + (size_t)(q0+lr)*LD + kk*32 + lq*8);
    short8 sc;
    #pragma unroll
    for (int j=0;j<8;++j) sc[j] = (short)f2b(b2f((u16)raw[j])*QSC);
    aq[kk]=sc;
  }

  float mrun = -3e38f, lrun = 0.f;
  f32x4 Oacc[4];
  #pragma unroll
  for (int dt=0;dt<4;++dt) Oacc[dt] = f32x4{0.f,0.f,0.f,0.f};

  int kc = (l&7) ^ (l>>3);
  int ra = 8*w + (l>>3);

  // prologue: stage tile 0
  async16(Kp  + (size_t)ra*LD        + kc*8, Ks[0] + t*8);
  async16(Kp  + (size_t)(ra+32)*LD   + kc*8, Ks[0] + 2048 + t*8);
  async16(Vtp + (size_t)ra*2048      + kc*8, Vs[0] + t*8);
  async16(Vtp + (size_t)(ra+32)*2048 + kc*8, Vs[0] + 2048 + t*8);

  for (int it=0; it<=qt; ++it){
    int s0 = it*64, cur = it&1;
    __syncthreads();
    if (it < qt){
      int sn = s0+64;
      u16* kd = Ks[cur^1]; u16* vd = Vs[cur^1];
      async16(Kp  + (size_t)(sn+ra)*LD        + kc*8, kd + t*8);
      async16(Kp  + (size_t)(sn+ra+32)*LD     + kc*8, kd + 2048 + t*8);
      async16(Vtp + (size_t)ra*2048      + sn + kc*8, vd + t*8);
      async16(Vtp + (size_t)(ra+32)*2048 + sn + kc*8, vd + 2048 + t*8);
    }
    const u16* ks = Ks[cur];
    const u16* vs = Vs[cur];

    // S^T[s][q] for this wave's 16 q
    f32x4 S[4];
    #pragma unroll
    for (int st=0; st<4; ++st){
      short8 kf0 = *(const short8*)(ks + (st*16+lr)*64 + ((lq  )^(lr&7))*8);
      short8 kf1 = *(const short8*)(ks + (st*16+lr)*64 + ((4+lq)^(lr&7))*8);
      f32x4 z = f32x4{0.f,0.f,0.f,0.f};
      z = __builtin_amdgcn_mfma_f32_16x16x32_bf16(kf0, aq[0], z, 0,0,0);
      z = __builtin_amdgcn_mfma_f32_16x16x32_bf16(kf1, aq[1], z, 0,0,0);
      S[st] = z;
    }
    if (it == qt){
      int qg = q0 + lr;
      #pragma unroll
      for (int st=0;st<4;++st)
        #pragma unroll
        for (int r=0;r<4;++r){
          int sg = s0 + st*16 + lq*4 + r;
          if (sg > qg) S[st][r] = -3e38f;
        }
    }
    // online softmax (q = lr; s-reduction in-lane + 2 shuffles)
    float m = S[0][0];
    #pragma unroll
    for (int st=0;st<4;++st)
      #pragma unroll
      for (int r=0;r<4;++r) m = fmaxf(m, S[st][r]);
    m = fmaxf(m, __shfl_xor(m,16));
    m = fmaxf(m, __shfl_xor(m,32));
    float mnew = fmaxf(mrun, m);
    float alpha = EXP2F(mrun - mnew);
    mrun = mnew;
    float ssum = 0.f;
    #pragma unroll
    for (int st=0;st<4;++st)
      #pragma unroll
      for (int r=0;r<4;++r){ float p = EXP2F(S[st][r]-mnew); S[st][r]=p; ssum+=p; }
    ssum += __shfl_xor(ssum,16);
    ssum += __shfl_xor(ssum,32);
    lrun = lrun*alpha + ssum;
    // P: in-lane pack to K=16 A-fragments
    short4_t pk[4];
    #pragma unroll
    for (int st=0;st<4;++st) pk[st] = pack4(S[st]);
    // rescale O (O rows: q = lq*4+r)
    float af[4];
    #pragma unroll
    for (int r=0;r<4;++r) af[r] = __shfl(alpha, lq*4+r);
    #pragma unroll
    for (int dt=0;dt<4;++dt)
      #pragma unroll
      for (int r=0;r<4;++r) Oacc[dt][r] *= af[r];
    // PV: 16 x mfma_16x16x16
    #pragma unroll
    for (int st=0;st<4;++st){
      #pragma unroll
      for (int dt=0;dt<4;++dt){
        short4_t vf = *(const short4_t*)(vs + (dt*16+lr)*64 + ((2*st+(lq>>1))^(lr&7))*8 + (lq&1)*4);
        Oacc[dt] = MFMA16(pk[st], vf, Oacc[dt]);
      }
    }
  }
  float linv[4];
  #pragma unroll
  for (int r=0;r<4;++r) linv[r] = 1.0f/__shfl(lrun, lq*4+r);
  #pragma unroll
  for (int dt=0;dt<4;++dt)
    #pragma unroll
    for (int r=0;r<4;++r){
      int qg = q0 + lq*4 + r;
      O[(size_t)(bb*T+qg)*E + h*64 + dt*16 + lr] = f2b(Oacc[dt][r]*linv[r]);
    }
}

// ---------------- host ----------------
extern "C" void kernel_launch(void* const* d_in, const int* in_sizes, int n_in,
                              void* d_out, int out_size, void* d_ws, size_t ws_size,
                              hipStream_t stream)
{
  (void)in_sizes; (void)n_in; (void)out_size; (void)ws_size;
  const float* x     = (const float*)d_in[0];
  const float* wq    = (const float*)d_in[1];
  const float* wk    = (const float*)d_in[2];
  const float* wv    = (const float*)d_in[3];
  const float* wproj = (const float*)d_in[4];
  const float* bproj = (const float*)d_in[5];
  const float* g1    = (const float*)d_in[6];
  const float* be1   = (const float*)d_in[7];
  const float* g2    = (const float*)d_in[8];
  const float* be2   = (const float*)d_in[9];
  const float* w1    = (const float*)d_in[10];
  const float* b1    = (const float*)d_in[11];
  const float* w2    = (const float*)d_in[12];
  const float* b2    = (const float*)d_in[13];
  float* out = (float*)d_out;

  char* ws = (char*)d_ws;
  size_t off = 0;
  auto alloc = [&](size_t bytes)->void*{ void* p = ws + off; off += (bytes + 255) & ~(size_t)255; return p; };
  u16* hnorm  = (u16*)alloc((size_t)4096*1024*2);
  u16* qkv    = (u16*)alloc((size_t)4096*3072*2);
  u16* VT     = (u16*)alloc((size_t)32*64*2048*2);
  u16* attnO  = (u16*)alloc((size_t)4096*1024*2);
  u16* x2     = (u16*)alloc((size_t)4096*1024*2);
  u16* h2     = (u16*)alloc((size_t)4096*1024*2);
  u16* ffn1   = (u16*)alloc((size_t)4096*4096*2);
  u16* wqkvT  = (u16*)alloc((size_t)3072*1024*2);
  u16* wprojT = (u16*)alloc((size_t)1024*1024*2);
  u16* w1T    = (u16*)alloc((size_t)4096*1024*2);
  u16* w2T    = (u16*)alloc((size_t)1024*4096*2);

  qkv_repack  <<<dim3(16,48),256,0,stream>>>(wq,wk,wv,wqkvT);
  transpose_bt<<<dim3(16,16),256,0,stream>>>(wproj, wprojT, 1024, 1024);
  transpose_bt<<<dim3(64,16),256,0,stream>>>(w1,    w1T,    4096, 1024);
  transpose_bt<<<dim3(16,64),256,0,stream>>>(w2,    w2T,    1024, 4096);

  ln_kernel<1><<<4096,256,0,stream>>>(x, g1, be1, hnorm);
  gemm256<<<dim3(12,16),512,0,stream>>>(hnorm, wqkvT, qkv, nullptr, 3072, 1024, nullptr, nullptr, 0, 4);
  vtrans<<<dim3(32,32),256,0,stream>>>(qkv, VT);
  attn_kernel<<<dim3(32,32),256,0,stream>>>(qkv, VT, attnO);
  gemm_bt<2><<<dim3(8,64),256,0,stream>>>(attnO, wprojT, x2, nullptr, 4096,1024,1024, bproj, hnorm, 0, 2);
  ln_kernel<0><<<4096,256,0,stream>>>(x2, g2, be2, h2);
  gemm256<<<dim3(16,16),512,0,stream>>>(h2, w1T, ffn1, nullptr, 4096, 1024, b1, nullptr, 1, 4);
  gemm_bt<2><<<dim3(8,64),256,0,stream>>>(ffn1, w2T, nullptr, out, 4096,1024,4096, b2, h2, 0, 2);
}

// Round 9
// 355.021 us; speedup vs baseline: 1.1095x; 1.0099x over previous
//
#include <hip/hip_runtime.h>
#include <stdint.h>

typedef unsigned short u16;
typedef __attribute__((ext_vector_type(8))) short short8;
typedef __attribute__((ext_vector_type(4))) short short4_t;
typedef __attribute__((ext_vector_type(4))) float f32x4;

__device__ __forceinline__ float b2f(u16 u){ union{unsigned i; float f;}v; v.i=((unsigned)u)<<16; return v.f; }
__device__ __forceinline__ u16 f2b(float f){ unsigned x=__float_as_uint(f); return (u16)((x + 0x7fffu + ((x>>16)&1u))>>16); }

#if __has_builtin(__builtin_amdgcn_exp2f)
#define EXP2F(x) __builtin_amdgcn_exp2f(x)
#else
#define EXP2F(x) exp2f(x)
#endif

#if __has_builtin(__builtin_amdgcn_mfma_f32_16x16x16_bf16)
#define MFMA16(a,b,c) __builtin_amdgcn_mfma_f32_16x16x16_bf16(a,b,c,0,0,0)
#elif __has_builtin(__builtin_amdgcn_mfma_f32_16x16x16bf16_1k)
#define MFMA16(a,b,c) __builtin_amdgcn_mfma_f32_16x16x16bf16_1k(a,b,c,0,0,0)
#else
static __device__ __forceinline__ f32x4 mfma16_asm(short4_t a, short4_t b, f32x4 c){
  __asm__("v_mfma_f32_16x16x16_bf16 %0, %1, %2, %3" : "=v"(c) : "v"(a), "v"(b), "0"(c));
  return c;
}
#define MFMA16(a,b,c) mfma16_asm(a,b,c)
#endif

__device__ __forceinline__ void async16(const void* g, void* l){
  __builtin_amdgcn_global_load_lds((const __attribute__((address_space(1))) void*)g,
                                   (__attribute__((address_space(3))) void*)l, 16, 0, 0);
}

// pack 4 fp32 (in [0,1]) -> 4 bf16 (round-half-up) as K=16 A-fragment regs
__device__ __forceinline__ short4_t pack4(f32x4 s){
  unsigned u0 = (__float_as_uint(s[0]) + 0x8000u) >> 16;
  unsigned u1 = (__float_as_uint(s[1]) + 0x8000u) & 0xffff0000u;
  unsigned u2 = (__float_as_uint(s[2]) + 0x8000u) >> 16;
  unsigned u3 = (__float_as_uint(s[3]) + 0x8000u) & 0xffff0000u;
  union { unsigned v[2]; short4_t s4; } r;
  r.v[0] = u0 | u1; r.v[1] = u2 | u3;
  return r.s4;
}

// ---------------- LayerNorm (E=1024, one block per row) ----------------
template<int IN_F32>
__global__ __launch_bounds__(256) void ln_kernel(const void* __restrict__ xin,
    const float* __restrict__ g, const float* __restrict__ b, u16* __restrict__ y)
{
  const int E = 1024;
  int row = blockIdx.x, t = threadIdx.x;
  float f0,f1,f2,f3;
  if (IN_F32){
    const float* xr = (const float*)xin + (size_t)row*E;
    float4 xv = *(const float4*)(xr + t*4);
    f0=xv.x; f1=xv.y; f2=xv.z; f3=xv.w;
  } else {
    const u16* xr = (const u16*)xin + (size_t)row*E;
    ushort4 xv = *(const ushort4*)(xr + t*4);
    f0=b2f(xv.x); f1=b2f(xv.y); f2=b2f(xv.z); f3=b2f(xv.w);
  }
  float s1 = f0+f1+f2+f3;
  float s2 = f0*f0+f1*f1+f2*f2+f3*f3;
  #pragma unroll
  for (int off=32; off>=1; off>>=1){ s1 += __shfl_xor(s1,off); s2 += __shfl_xor(s2,off); }
  __shared__ float red[8];
  int w = t>>6;
  if ((t&63)==0){ red[w]=s1; red[4+w]=s2; }
  __syncthreads();
  float S1 = red[0]+red[1]+red[2]+red[3];
  float S2 = red[4]+red[5]+red[6]+red[7];
  float mean = S1*(1.0f/E);
  float var  = S2*(1.0f/E) - mean*mean;
  float inv  = rsqrtf(var + 1e-5f);
  float4 gv = *(const float4*)(g + t*4);
  float4 bv = *(const float4*)(b + t*4);
  ushort4 o;
  o.x = f2b((f0-mean)*inv*gv.x+bv.x);
  o.y = f2b((f1-mean)*inv*gv.y+bv.y);
  o.z = f2b((f2-mean)*inv*gv.z+bv.z);
  o.w = f2b((f3-mean)*inv*gv.w+bv.w);
  *(ushort4*)(y + (size_t)row*E + t*4) = o;
}

// ---------------- fp32->bf16 64x64-tiled transpose ----------------
__global__ __launch_bounds__(256) void transpose_bt(const float* __restrict__ src, u16* __restrict__ dst,
                                                    int ld_src, int ld_dst)
{
  __shared__ u16 tile[64*66];
  int c0 = blockIdx.x*64, r0 = blockIdx.y*64;
  int t = threadIdx.x;
  #pragma unroll
  for (int i=0;i<16;++i){
    int lin = i*256 + t;
    int rr = lin>>6, cc = lin&63;
    tile[cc*66+rr] = f2b(src[(size_t)(r0+rr)*ld_src + c0+cc]);
  }
  __syncthreads();
  #pragma unroll
  for (int i=0;i<16;++i){
    int lin = i*256 + t;
    int cc = lin>>6, rr = lin&63;
    dst[(size_t)(c0+cc)*ld_dst + r0+rr] = tile[cc*66+rr];
  }
}

// ---------------- QKV weight repack ----------------
__global__ __launch_bounds__(256) void qkv_repack(const float* __restrict__ wq, const float* __restrict__ wk,
                                                  const float* __restrict__ wv, u16* __restrict__ dst)
{
  __shared__ u16 tile[64*66];
  int e0 = blockIdx.x*64;
  int sel = blockIdx.y>>4, h = blockIdx.y&15;
  const float* src = (sel==0?wq:(sel==1?wk:wv)) + (size_t)h*1024*64;
  int t = threadIdx.x;
  #pragma unroll
  for (int i=0;i<16;++i){
    int lin=i*256+t; int rr=lin>>6, cc=lin&63;
    tile[cc*66+rr] = f2b(src[(size_t)(e0+rr)*64 + cc]);
  }
  __syncthreads();
  #pragma unroll
  for (int i=0;i<16;++i){
    int lin=i*256+t; int cc=lin>>6, rr=lin&63;
    dst[(size_t)(sel*1024 + h*64 + cc)*1024 + e0+rr] = tile[cc*66+rr];
  }
}

// ---------------- V transpose: qkv V-slice -> VT[bh][64][2048] ----------------
__global__ __launch_bounds__(256) void vtrans(const u16* __restrict__ qkv, u16* __restrict__ VT)
{
  __shared__ u16 tile[64*66];
  int bh = blockIdx.y, bb = bh>>4, h = bh&15;
  int s0 = blockIdx.x*64;
  const u16* src = qkv + ((size_t)(bb*2048) + s0)*3072 + 2048 + h*64;
  int t = threadIdx.x;
  int sr = t>>3, c0 = (t&7)*8;
  #pragma unroll
  for (int half=0; half<2; ++half){
    const u16* p = src + (size_t)(sr+half*32)*3072 + c0;
    ushort4 v0 = *(const ushort4*)p;
    ushort4 v1 = *(const ushort4*)(p+4);
    uint* d = (uint*)(tile + (sr+half*32)*66 + c0);
    d[0] = (uint)v0.x | ((uint)v0.y<<16);
    d[1] = (uint)v0.z | ((uint)v0.w<<16);
    d[2] = (uint)v1.x | ((uint)v1.y<<16);
    d[3] = (uint)v1.z | ((uint)v1.w<<16);
  }
  __syncthreads();
  u16* out = VT + (size_t)bh*64*2048 + s0;
  int dw = t>>3, sc = (t&7)*8;
  #pragma unroll
  for (int half=0; half<2; ++half){
    int d = dw + half*32;
    short8 pk;
    #pragma unroll
    for (int j=0;j<8;++j) pk[j] = (short)tile[(sc+j)*66 + d];
    *(short8*)(out + (size_t)d*2048 + sc) = pk;
  }
}

// ---------------- bf16 GEMM: C[M][N] = A[M][K] * Bt[N][K]^T (legacy 2-phase) ----------------
template<int MI>
__global__ __launch_bounds__(256, 3) void gemm_bt(const u16* __restrict__ A, const u16* __restrict__ Bt,
    u16* __restrict__ C, float* __restrict__ Cf, int M, int N, int K,
    const float* __restrict__ bias, const u16* __restrict__ residual, int do_relu, int gx)
{
  __shared__ __align__(16) u16 As[2][MI*32*64];
  __shared__ __align__(16) u16 Bs[2][128*64];
  int t = threadIdx.x;
  int bid = blockIdx.y * gridDim.x + blockIdx.x;
  int xcd = bid & 7, slot = bid >> 3;
  int gy = 8 / gx;
  int rx = gridDim.x / gx, ry = gridDim.y / gy;
  int col_b = (xcd % gx) * rx + (slot % rx);
  int row_b = (xcd / gx) * ry + (slot / rx);
  int row0 = row_b*(MI*32), col0 = col_b*128;
  int l = t&63, w = t>>6;
  int wm = (w>>1)*(MI*16), wn = (w&1)*64;
  int lr = l&15, lq = l>>4;
  (void)M;

  f32x4 acc[MI][4];
  #pragma unroll
  for (int i=0;i<MI;++i)
    #pragma unroll
    for (int j=0;j<4;++j) acc[i][j] = f32x4{0.f,0.f,0.f,0.f};

  const u16* gA = A  + (size_t)(row0 + (t>>3))*K + (((t&7)^((t>>3)&7))<<3);
  const u16* gB = Bt + (size_t)(col0 + (t>>3))*K + (((t&7)^((t>>3)&7))<<3);
  const size_t rnd = (size_t)32*K;
  int nk = K>>6;

  #pragma unroll
  for (int r=0;r<MI;++r) async16(gA + r*rnd, As[0] + r*2048 + t*8);
  #pragma unroll
  for (int r=0;r<4;++r)  async16(gB + r*rnd, Bs[0] + r*2048 + t*8);

  int sw8 = (lr&7);
  for (int kt=0; kt<nk; ++kt){
    int cur = kt&1;
    __syncthreads();
    if (kt+1 < nk){
      int ko = (kt+1)<<6;
      #pragma unroll
      for (int r=0;r<MI;++r) async16(gA + r*rnd + ko, As[cur^1] + r*2048 + t*8);
      #pragma unroll
      for (int r=0;r<4;++r)  async16(gB + r*rnd + ko, Bs[cur^1] + r*2048 + t*8);
    }
    const u16* as = As[cur];
    const u16* bs = Bs[cur];
    #pragma unroll
    for (int kk=0;kk<2;++kk){
      int so = (((kk*4+lq)^sw8))<<3;
      short8 a[MI], b[4];
      #pragma unroll
      for (int i=0;i<MI;++i) a[i] = *(const short8*)(as + (wm+i*16+lr)*64 + so);
      #pragma unroll
      for (int j=0;j<4;++j)  b[j] = *(const short8*)(bs + (wn+j*16+lr)*64 + so);
      #pragma unroll
      for (int i=0;i<MI;++i)
        #pragma unroll
        for (int j=0;j<4;++j)
          acc[i][j] = __builtin_amdgcn_mfma_f32_16x16x32_bf16(a[i], b[j], acc[i][j], 0,0,0);
    }
  }

  #pragma unroll
  for (int i=0;i<MI;++i){
    #pragma unroll
    for (int j=0;j<4;++j){
      int col = col0 + wn + j*16 + lr;
      float bv = bias ? bias[col] : 0.0f;
      #pragma unroll
      for (int r=0;r<4;++r){
        int row = row0 + wm + i*16 + lq*4 + r;
        float v = acc[i][j][r] + bv;
        if (do_relu) v = fmaxf(v, 0.0f);
        if (residual) v += b2f(residual[(size_t)row*N + col]);
        if (Cf) Cf[(size_t)row*N + col] = v;
        else    C [(size_t)row*N + col] = f2b(v);
      }
    }
  }
}

// ---------------- bf16 GEMM 256x256 tile, 8 waves, 4-phase/K-tile ----------------
// v5: v4's staging/wait schedule UNCHANGED (1 half-tile staged per phase;
// vmcnt(8) only at p_b/p_d; same FIFO ledger) but ALL manual lgkmcnt(0) and
// sched_barrier(0) pins REMOVED.  ds_reads are compiler-visible C++ loads —
// hipcc tracks read->MFMA deps and emits fine-grained partial lgkmcnt, and can
// stagger per-wave read/MFMA starts across the barrier (the m141 lesson:
// order-pinning + full drains defeat the compiler's scheduling).  Correctness:
// counted vmcnt asm ("memory" clobber) still fences LDS reads against async
// global_load_lds writes; raw s_barrier (side-effecting) orders cross-wave.
__global__ __launch_bounds__(512,2) void gemm256(const u16* __restrict__ A, const u16* __restrict__ Bt,
    u16* __restrict__ C, float* __restrict__ Cf, int N, int K,
    const float* __restrict__ bias, const u16* __restrict__ residual, int do_relu, int gx)
{
  __shared__ __align__(16) u16 As[2][256*64];
  __shared__ __align__(16) u16 Bs[2][256*64];
  int t = threadIdx.x;
  int bid = blockIdx.y*gridDim.x + blockIdx.x;
  int xcd = bid & 7, slot = bid >> 3;
  int gy = 8/gx;
  int rx = gridDim.x/gx, ry = gridDim.y/gy;
  int col_b = (xcd%gx)*rx + slot%rx;
  int row_b = (xcd/gx)*ry + slot/rx;
  int row0 = row_b*256, col0 = col_b*256;
  int l = t&63, w = t>>6;
  int wr = w>>2, wc = w&3;           // 2 x 4 wave grid, per-wave 128(M) x 64(N)
  int lr = l&15, lq = l>>4, sw = lr&7;

  f32x4 acc[8][4];
  #pragma unroll
  for (int m=0;m<8;++m)
    #pragma unroll
    for (int n=0;n<4;++n) acc[m][n] = f32x4{0.f,0.f,0.f,0.f};

  int i = t>>3, c8 = t&7;
  int swc = (c8 ^ (i&7))*8;
  const u16* aS[4]; const u16* bS[4];
  {
    int la[4] = { i, 128+i, 64+i, 192+i };
    #pragma unroll
    for (int s=0;s<4;++s){
      aS[s] = A + (size_t)(row0 + la[s])*K + swc;
      int p = s*64 + i;
      int lb = ((p>>5)&3)*64 + (p>>7)*32 + (p&31);
      bS[s] = Bt + (size_t)(col0 + lb)*K + swc;
    }
  }
  int nk = K>>6;   // requires nk >= 3

  u16* A0p = As[0]; u16* A1p = As[1];
  u16* B0p = Bs[0]; u16* B1p = Bs[1];

  short8 af[4][2], bP[2][2], bQ[2][2];

#define VM8  asm volatile("s_waitcnt vmcnt(8)" ::: "memory");
#define VM6  asm volatile("s_waitcnt vmcnt(6)" ::: "memory");
#define VM0  asm volatile("s_waitcnt vmcnt(0)" ::: "memory");
#define BAR  __builtin_amdgcn_s_barrier();

#define RD_A(BUF,qm) \
  _Pragma("unroll") \
  for (int mm=0;mm<4;++mm){ \
    _Pragma("unroll") \
    for (int kk=0;kk<2;++kk) \
      af[mm][kk] = *(const short8*)((const u16*)(BUF) + ((qm)*128 + wr*64 + mm*16 + lr)*64 + (((kk*4+lq)^sw)<<3)); \
  }
#define RD_B(DST,BUF,qn) \
  _Pragma("unroll") \
  for (int nn=0;nn<2;++nn){ \
    _Pragma("unroll") \
    for (int kk=0;kk<2;++kk) \
      DST[nn][kk] = *(const short8*)((const u16*)(BUF) + ((qn)*128 + wc*32 + nn*16 + lr)*64 + (((kk*4+lq)^sw)<<3)); \
  }
#define MMQ(qm,qn,BSS) \
  __builtin_amdgcn_s_setprio(1); \
  _Pragma("unroll") \
  for (int mm=0;mm<4;++mm){ \
    _Pragma("unroll") \
    for (int nn=0;nn<2;++nn){ \
      _Pragma("unroll") \
      for (int kk=0;kk<2;++kk) \
        acc[(qm)*4+mm][(qn)*2+nn] = __builtin_amdgcn_mfma_f32_16x16x32_bf16(af[mm][kk], BSS[nn][kk], acc[(qm)*4+mm][(qn)*2+nn], 0,0,0); \
    } \
  } \
  __builtin_amdgcn_s_setprio(0);

  // prologue: 14 loads — tile0 {A0,B0,B1,A1} -> buf0; tile1 {A0,B0,B1} -> buf1
  async16(aS[0], A0p + 0*4096 + t*8);
  async16(aS[1], A0p + 1*4096 + t*8);
  async16(bS[0], B0p + 0*4096 + t*8);
  async16(bS[1], B0p + 1*4096 + t*8);
  async16(bS[2], B0p + 2*4096 + t*8);
  async16(bS[3], B0p + 3*4096 + t*8);
  async16(aS[2], A0p + 2*4096 + t*8);
  async16(aS[3], A0p + 3*4096 + t*8);
  async16(aS[0]+64, A1p + 0*4096 + t*8);
  async16(aS[1]+64, A1p + 1*4096 + t*8);
  async16(bS[0]+64, B1p + 0*4096 + t*8);
  async16(bS[1]+64, B1p + 1*4096 + t*8);
  async16(bS[2]+64, B1p + 2*4096 + t*8);
  async16(bS[3]+64, B1p + 3*4096 + t*8);
  VM8; BAR;                               // retires tile0 {A0,B0,B1}
  RD_A(A0p, 0); RD_B(bP, B0p, 0);

  for (int kt=0; kt<nk-1; ++kt){
    int cur = kt&1;
    u16* Ac = As[cur]; u16* Bc = Bs[cur];
    u16* An = As[cur^1]; u16* Bn = Bs[cur^1];
    int ko1 = (kt+1)<<6;
    int kc2 = (kt+2 < nk) ? kt+2 : nk-1;
    int ko2 = kc2<<6;
    // p_a: MMQ(0,0); stage A1(k+1)->next buf
    async16(aS[2]+ko1, An + 2*4096 + t*8);
    async16(aS[3]+ko1, An + 3*4096 + t*8);
    BAR;
    MMQ(0,0,bP);
    RD_B(bQ, Bc, 1);
    BAR;
    // p_b: MMQ(0,1); stage B1(k+2)->cur buf; wait
    async16(bS[2]+ko2, Bc + 2*4096 + t*8);
    async16(bS[3]+ko2, Bc + 3*4096 + t*8);
    VM8; BAR;
    MMQ(0,1,bQ);
    RD_A(Ac, 1);
    BAR;
    // p_c: MMQ(1,1); stage A0(k+2)->cur buf
    async16(aS[0]+ko2, Ac + 0*4096 + t*8);
    async16(aS[1]+ko2, Ac + 1*4096 + t*8);
    BAR;
    MMQ(1,1,bQ);
    BAR;
    // p_d: MMQ(1,0); stage B0(k+2)->cur buf; wait; prefetch-read next A0,B0
    async16(bS[0]+ko2, Bc + 0*4096 + t*8);
    async16(bS[1]+ko2, Bc + 1*4096 + t*8);
    VM8; BAR;
    MMQ(1,0,bP);
    RD_A(An, 0); RD_B(bP, Bn, 0);
    BAR;
  }
  { // tail tile (nk-1): no staging
    int cur = (nk-1)&1;
    u16* Ac = As[cur]; u16* Bc = Bs[cur];
    BAR;
    MMQ(0,0,bP);
    RD_B(bQ, Bc, 1);
    BAR;
    VM6; BAR;                             // retires A1(nk-1)
    MMQ(0,1,bQ);
    RD_A(Ac, 1);
    MMQ(1,1,bQ);
    MMQ(1,0,bP);
  }
  VM0;   // drain remaining async LDS writes before epilogue

#undef VM8
#undef VM6
#undef VM0
#undef BAR
#undef RD_A
#undef RD_B
#undef MMQ

  #pragma unroll
  for (int m=0;m<8;++m){
    #pragma unroll
    for (int n=0;n<4;++n){
      int col = col0 + wc*64 + n*16 + lr;
      float bv = bias ? bias[col] : 0.0f;
      #pragma unroll
      for (int r=0;r<4;++r){
        int row = row0 + wr*128 + m*16 + lq*4 + r;
        float v = acc[m][n][r] + bv;
        if (do_relu) v = fmaxf(v, 0.0f);
        if (residual) v += b2f(residual[(size_t)row*N + col]);
        if (Cf) Cf[(size_t)row*N + col] = v;
        else    C [(size_t)row*N + col] = f2b(v);
      }
    }
  }
}

// ---------------- causal flash attention v4 ----------------
// Q-tile 64 (4 waves x 16 q rows), s-tile 64 double-buffered, grid 1024.
// S^T via K=32 mfma; P stays IN-LANE (C-layout == K=16 A-layout), PV via
// 16x16x16 mfma on packed bf16 — no P LDS round-trip. Complementary-qt
// slot pairing balances per-CU work. K and V^T staged via global_load_lds.
__global__ __launch_bounds__(256,4) void attn_kernel(const u16* __restrict__ QKV,
    const u16* __restrict__ VT, u16* __restrict__ O)
{
  const int T=2048, LD=3072, E=1024;
  int bid = blockIdx.y * gridDim.x + blockIdx.x;
  int xcd = bid & 7, slot = bid >> 3;
  int idx = slot & 31, grp = slot >> 5;
  int qt = (grp & 1) ? idx : 31 - idx;   // heavy-first, complementary pairing
  int bh = xcd*4 + grp;
  int bb = bh>>4, h = bh&15;
  const u16* base = QKV + (size_t)bb*T*LD;
  const u16* Qp = base + h*64;
  const u16* Kp = base + 1024 + h*64;
  const u16* Vtp = VT + (size_t)bh*64*2048;
  int t = threadIdx.x, l = t&63, w = t>>6;
  int lr = l&15, lq = l>>4;

  __shared__ __align__(16) u16 Ks[2][64*64];   // [s][d], chunk c at slot c^(s&7)
  __shared__ __align__(16) u16 Vs[2][64*64];   // [d][s], chunk c at slot c^(d&7)

  const float QSC = 0.125f*1.44269504f;
  int q0 = qt*64 + w*16;
  short8 aq[2];
  #pragma unroll
  for (int kk=0;kk<2;++kk){
    short8 raw = *(const short8*)(Qp + (size_t)(q0+lr)*LD + kk*32 + lq*8);
    short8 sc;
    #pragma unroll
    for (int j=0;j<8;++j) sc[j] = (short)f2b(b2f((u16)raw[j])*QSC);
    aq[kk]=sc;
  }

  float mrun = -3e38f, lrun = 0.f;
  f32x4 Oacc[4];
  #pragma unroll
  for (int dt=0;dt<4;++dt) Oacc[dt] = f32x4{0.f,0.f,0.f,0.f};

  int kc = (l&7) ^ (l>>3);
  int ra = 8*w + (l>>3);

  // prologue: stage tile 0
  async16(Kp  + (size_t)ra*LD        + kc*8, Ks[0] + t*8);
  async16(Kp  + (size_t)(ra+32)*LD   + kc*8, Ks[0] + 2048 + t*8);
  async16(Vtp + (size_t)ra*2048      + kc*8, Vs[0] + t*8);
  async16(Vtp + (size_t)(ra+32)*2048 + kc*8, Vs[0] + 2048 + t*8);

  for (int it=0; it<=qt; ++it){
    int s0 = it*64, cur = it&1;
    __syncthreads();
    if (it < qt){
      int sn = s0+64;
      u16* kd = Ks[cur^1]; u16* vd = Vs[cur^1];
      async16(Kp  + (size_t)(sn+ra)*LD        + kc*8, kd + t*8);
      async16(Kp  + (size_t)(sn+ra+32)*LD     + kc*8, kd + 2048 + t*8);
      async16(Vtp + (size_t)ra*2048      + sn + kc*8, vd + t*8);
      async16(Vtp + (size_t)(ra+32)*2048 + sn + kc*8, vd + 2048 + t*8);
    }
    const u16* ks = Ks[cur];
    const u16* vs = Vs[cur];

    // S^T[s][q] for this wave's 16 q
    f32x4 S[4];
    #pragma unroll
    for (int st=0; st<4; ++st){
      short8 kf0 = *(const short8*)(ks + (st*16+lr)*64 + ((lq  )^(lr&7))*8);
      short8 kf1 = *(const short8*)(ks + (st*16+lr)*64 + ((4+lq)^(lr&7))*8);
      f32x4 z = f32x4{0.f,0.f,0.f,0.f};
      z = __builtin_amdgcn_mfma_f32_16x16x32_bf16(kf0, aq[0], z, 0,0,0);
      z = __builtin_amdgcn_mfma_f32_16x16x32_bf16(kf1, aq[1], z, 0,0,0);
      S[st] = z;
    }
    if (it == qt){
      int qg = q0 + lr;
      #pragma unroll
      for (int st=0;st<4;++st)
        #pragma unroll
        for (int r=0;r<4;++r){
          int sg = s0 + st*16 + lq*4 + r;
          if (sg > qg) S[st][r] = -3e38f;
        }
    }
    // online softmax (q = lr; s-reduction in-lane + 2 shuffles)
    float m = S[0][0];
    #pragma unroll
    for (int st=0;st<4;++st)
      #pragma unroll
      for (int r=0;r<4;++r) m = fmaxf(m, S[st][r]);
    m = fmaxf(m, __shfl_xor(m,16));
    m = fmaxf(m, __shfl_xor(m,32));
    float mnew = fmaxf(mrun, m);
    float alpha = EXP2F(mrun - mnew);
    mrun = mnew;
    float ssum = 0.f;
    #pragma unroll
    for (int st=0;st<4;++st)
      #pragma unroll
      for (int r=0;r<4;++r){ float p = EXP2F(S[st][r]-mnew); S[st][r]=p; ssum+=p; }
    ssum += __shfl_xor(ssum,16);
    ssum += __shfl_xor(ssum,32);
    lrun = lrun*alpha + ssum;
    // P: in-lane pack to K=16 A-fragments
    short4_t pk[4];
    #pragma unroll
    for (int st=0;st<4;++st) pk[st] = pack4(S[st]);
    // rescale O (O rows: q = lq*4+r)
    float af[4];
    #pragma unroll
    for (int r=0;r<4;++r) af[r] = __shfl(alpha, lq*4+r);
    #pragma unroll
    for (int dt=0;dt<4;++dt)
      #pragma unroll
      for (int r=0;r<4;++r) Oacc[dt][r] *= af[r];
    // PV: 16 x mfma_16x16x16
    #pragma unroll
    for (int st=0;st<4;++st){
      #pragma unroll
      for (int dt=0;dt<4;++dt){
        short4_t vf = *(const short4_t*)(vs + (dt*16+lr)*64 + ((2*st+(lq>>1))^(lr&7))*8 + (lq&1)*4);
        Oacc[dt] = MFMA16(pk[st], vf, Oacc[dt]);
      }
    }
  }
  float linv[4];
  #pragma unroll
  for (int r=0;r<4;++r) linv[r] = 1.0f/__shfl(lrun, lq*4+r);
  #pragma unroll
  for (int dt=0;dt<4;++dt)
    #pragma unroll
    for (int r=0;r<4;++r){
      int qg = q0 + lq*4 + r;
      O[(size_t)(bb*T+qg)*E + h*64 + dt*16 + lr] = f2b(Oacc[dt][r]*linv[r]);
    }
}

// ---------------- host ----------------
extern "C" void kernel_launch(void* const* d_in, const int* in_sizes, int n_in,
                              void* d_out, int out_size, void* d_ws, size_t ws_size,
                              hipStream_t stream)
{
  (void)in_sizes; (void)n_in; (void)out_size; (void)ws_size;
  const float* x     = (const float*)d_in[0];
  const float* wq    = (const float*)d_in[1];
  const float* wk    = (const float*)d_in[2];
  const float* wv    = (const float*)d_in[3];
  const float* wproj = (const float*)d_in[4];
  const float* bproj = (const float*)d_in[5];
  const float* g1    = (const float*)d_in[6];
  const float* be1   = (const float*)d_in[7];
  const float* g2    = (const float*)d_in[8];
  const float* be2   = (const float*)d_in[9];
  const float* w1    = (const float*)d_in[10];
  const float* b1    = (const float*)d_in[11];
  const float* w2    = (const float*)d_in[12];
  const float* b2    = (const float*)d_in[13];
  float* out = (float*)d_out;

  char* ws = (char*)d_ws;
  size_t off = 0;
  auto alloc = [&](size_t bytes)->void*{ void* p = ws + off; off += (bytes + 255) & ~(size_t)255; return p; };
  u16* hnorm  = (u16*)alloc((size_t)4096*1024*2);
  u16* qkv    = (u16*)alloc((size_t)4096*3072*2);
  u16* VT     = (u16*)alloc((size_t)32*64*2048*2);
  u16* attnO  = (u16*)alloc((size_t)4096*1024*2);
  u16* x2     = (u16*)alloc((size_t)4096*1024*2);
  u16* h2     = (u16*)alloc((size_t)4096*1024*2);
  u16* ffn1   = (u16*)alloc((size_t)4096*4096*2);
  u16* wqkvT  = (u16*)alloc((size_t)3072*1024*2);
  u16* wprojT = (u16*)alloc((size_t)1024*1024*2);
  u16* w1T    = (u16*)alloc((size_t)4096*1024*2);
  u16* w2T    = (u16*)alloc((size_t)1024*4096*2);

  qkv_repack  <<<dim3(16,48),256,0,stream>>>(wq,wk,wv,wqkvT);
  transpose_bt<<<dim3(16,16),256,0,stream>>>(wproj, wprojT, 1024, 1024);
  transpose_bt<<<dim3(64,16),256,0,stream>>>(w1,    w1T,    4096, 1024);
  transpose_bt<<<dim3(16,64),256,0,stream>>>(w2,    w2T,    1024, 4096);

  ln_kernel<1><<<4096,256,0,stream>>>(x, g1, be1, hnorm);
  gemm256<<<dim3(12,16),512,0,stream>>>(hnorm, wqkvT, qkv, nullptr, 3072, 1024, nullptr, nullptr, 0, 4);
  vtrans<<<dim3(32,32),256,0,stream>>>(qkv, VT);
  attn_kernel<<<dim3(32,32),256,0,stream>>>(qkv, VT, attnO);
  gemm_bt<2><<<dim3(8,64),256,0,stream>>>(attnO, wprojT, x2, nullptr, 4096,1024,1024, bproj, hnorm, 0, 2);
  ln_kernel<0><<<4096,256,0,stream>>>(x2, g2, be2, h2);
  gemm256<<<dim3(16,16),512,0,stream>>>(h2, w1T, ffn1, nullptr, 4096, 1024, b1, nullptr, 1, 4);
  gemm_bt<2><<<dim3(8,64),256,0,stream>>>(ffn1, w2T, nullptr, out, 4096,1024,4096, b2, h2, 0, 2);
}

// Round 10
// 348.244 us; speedup vs baseline: 1.1311x; 1.0195x over previous
//
#include <hip/hip_runtime.h>
#include <stdint.h>

typedef unsigned short u16;
typedef __attribute__((ext_vector_type(8))) short short8;
typedef __attribute__((ext_vector_type(4))) short short4_t;
typedef __attribute__((ext_vector_type(4))) float f32x4;

__device__ __forceinline__ float b2f(u16 u){ union{unsigned i; float f;}v; v.i=((unsigned)u)<<16; return v.f; }
__device__ __forceinline__ u16 f2b(float f){ unsigned x=__float_as_uint(f); return (u16)((x + 0x7fffu + ((x>>16)&1u))>>16); }

#if __has_builtin(__builtin_amdgcn_exp2f)
#define EXP2F(x) __builtin_amdgcn_exp2f(x)
#else
#define EXP2F(x) exp2f(x)
#endif

#if __has_builtin(__builtin_amdgcn_mfma_f32_16x16x16_bf16)
#define MFMA16(a,b,c) __builtin_amdgcn_mfma_f32_16x16x16_bf16(a,b,c,0,0,0)
#elif __has_builtin(__builtin_amdgcn_mfma_f32_16x16x16bf16_1k)
#define MFMA16(a,b,c) __builtin_amdgcn_mfma_f32_16x16x16bf16_1k(a,b,c,0,0,0)
#else
static __device__ __forceinline__ f32x4 mfma16_asm(short4_t a, short4_t b, f32x4 c){
  __asm__("v_mfma_f32_16x16x16_bf16 %0, %1, %2, %3" : "=v"(c) : "v"(a), "v"(b), "0"(c));
  return c;
}
#define MFMA16(a,b,c) mfma16_asm(a,b,c)
#endif

__device__ __forceinline__ void async16(const void* g, void* l){
  __builtin_amdgcn_global_load_lds((const __attribute__((address_space(1))) void*)g,
                                   (__attribute__((address_space(3))) void*)l, 16, 0, 0);
}

// pack 4 fp32 (in [0,1]) -> 4 bf16 (round-half-up) as K=16 A-fragment regs
__device__ __forceinline__ short4_t pack4(f32x4 s){
  unsigned u0 = (__float_as_uint(s[0]) + 0x8000u) >> 16;
  unsigned u1 = (__float_as_uint(s[1]) + 0x8000u) & 0xffff0000u;
  unsigned u2 = (__float_as_uint(s[2]) + 0x8000u) >> 16;
  unsigned u3 = (__float_as_uint(s[3]) + 0x8000u) & 0xffff0000u;
  union { unsigned v[2]; short4_t s4; } r;
  r.v[0] = u0 | u1; r.v[1] = u2 | u3;
  return r.s4;
}

// ---------------- LayerNorm (E=1024, one block per row) ----------------
template<int IN_F32>
__global__ __launch_bounds__(256) void ln_kernel(const void* __restrict__ xin,
    const float* __restrict__ g, const float* __restrict__ b, u16* __restrict__ y)
{
  const int E = 1024;
  int row = blockIdx.x, t = threadIdx.x;
  float f0,f1,f2,f3;
  if (IN_F32){
    const float* xr = (const float*)xin + (size_t)row*E;
    float4 xv = *(const float4*)(xr + t*4);
    f0=xv.x; f1=xv.y; f2=xv.z; f3=xv.w;
  } else {
    const u16* xr = (const u16*)xin + (size_t)row*E;
    ushort4 xv = *(const ushort4*)(xr + t*4);
    f0=b2f(xv.x); f1=b2f(xv.y); f2=b2f(xv.z); f3=b2f(xv.w);
  }
  float s1 = f0+f1+f2+f3;
  float s2 = f0*f0+f1*f1+f2*f2+f3*f3;
  #pragma unroll
  for (int off=32; off>=1; off>>=1){ s1 += __shfl_xor(s1,off); s2 += __shfl_xor(s2,off); }
  __shared__ float red[8];
  int w = t>>6;
  if ((t&63)==0){ red[w]=s1; red[4+w]=s2; }
  __syncthreads();
  float S1 = red[0]+red[1]+red[2]+red[3];
  float S2 = red[4]+red[5]+red[6]+red[7];
  float mean = S1*(1.0f/E);
  float var  = S2*(1.0f/E) - mean*mean;
  float inv  = rsqrtf(var + 1e-5f);
  float4 gv = *(const float4*)(g + t*4);
  float4 bv = *(const float4*)(b + t*4);
  ushort4 o;
  o.x = f2b((f0-mean)*inv*gv.x+bv.x);
  o.y = f2b((f1-mean)*inv*gv.y+bv.y);
  o.z = f2b((f2-mean)*inv*gv.z+bv.z);
  o.w = f2b((f3-mean)*inv*gv.w+bv.w);
  *(ushort4*)(y + (size_t)row*E + t*4) = o;
}

// ---------------- fp32->bf16 64x64-tiled transpose ----------------
__global__ __launch_bounds__(256) void transpose_bt(const float* __restrict__ src, u16* __restrict__ dst,
                                                    int ld_src, int ld_dst)
{
  __shared__ u16 tile[64*66];
  int c0 = blockIdx.x*64, r0 = blockIdx.y*64;
  int t = threadIdx.x;
  #pragma unroll
  for (int i=0;i<16;++i){
    int lin = i*256 + t;
    int rr = lin>>6, cc = lin&63;
    tile[cc*66+rr] = f2b(src[(size_t)(r0+rr)*ld_src + c0+cc]);
  }
  __syncthreads();
  #pragma unroll
  for (int i=0;i<16;++i){
    int lin = i*256 + t;
    int cc = lin>>6, rr = lin&63;
    dst[(size_t)(c0+cc)*ld_dst + r0+rr] = tile[cc*66+rr];
  }
}

// ---------------- QKV weight repack ----------------
__global__ __launch_bounds__(256) void qkv_repack(const float* __restrict__ wq, const float* __restrict__ wk,
                                                  const float* __restrict__ wv, u16* __restrict__ dst)
{
  __shared__ u16 tile[64*66];
  int e0 = blockIdx.x*64;
  int sel = blockIdx.y>>4, h = blockIdx.y&15;
  const float* src = (sel==0?wq:(sel==1?wk:wv)) + (size_t)h*1024*64;
  int t = threadIdx.x;
  #pragma unroll
  for (int i=0;i<16;++i){
    int lin=i*256+t; int rr=lin>>6, cc=lin&63;
    tile[cc*66+rr] = f2b(src[(size_t)(e0+rr)*64 + cc]);
  }
  __syncthreads();
  #pragma unroll
  for (int i=0;i<16;++i){
    int lin=i*256+t; int cc=lin>>6, rr=lin&63;
    dst[(size_t)(sel*1024 + h*64 + cc)*1024 + e0+rr] = tile[cc*66+rr];
  }
}

// ---------------- V transpose: qkv V-slice -> VT[bh][64][2048] ----------------
__global__ __launch_bounds__(256) void vtrans(const u16* __restrict__ qkv, u16* __restrict__ VT)
{
  __shared__ u16 tile[64*66];
  int bh = blockIdx.y, bb = bh>>4, h = bh&15;
  int s0 = blockIdx.x*64;
  const u16* src = qkv + ((size_t)(bb*2048) + s0)*3072 + 2048 + h*64;
  int t = threadIdx.x;
  int sr = t>>3, c0 = (t&7)*8;
  #pragma unroll
  for (int half=0; half<2; ++half){
    const u16* p = src + (size_t)(sr+half*32)*3072 + c0;
    ushort4 v0 = *(const ushort4*)p;
    ushort4 v1 = *(const ushort4*)(p+4);
    uint* d = (uint*)(tile + (sr+half*32)*66 + c0);
    d[0] = (uint)v0.x | ((uint)v0.y<<16);
    d[1] = (uint)v0.z | ((uint)v0.w<<16);
    d[2] = (uint)v1.x | ((uint)v1.y<<16);
    d[3] = (uint)v1.z | ((uint)v1.w<<16);
  }
  __syncthreads();
  u16* out = VT + (size_t)bh*64*2048 + s0;
  int dw = t>>3, sc = (t&7)*8;
  #pragma unroll
  for (int half=0; half<2; ++half){
    int d = dw + half*32;
    short8 pk;
    #pragma unroll
    for (int j=0;j<8;++j) pk[j] = (short)tile[(sc+j)*66 + d];
    *(short8*)(out + (size_t)d*2048 + sc) = pk;
  }
}

// ---------------- gemm64: 64x64 tile, 4 waves, high-TLP (4 blocks/CU) ----------------
// Same proven 2-barrier K-loop as legacy gemm_bt, but 64-col B-tile and 16-row
// wave slices -> grid 4x larger for N=1024 shapes (FFN2, proj): 1024 blocks =
// 4 blocks/CU = 16 waves/CU (vs 2 blocks/8 waves before).  All GEMMs measured
// ~550 TF / MfmaUtil 20% / nothing saturated => latency-bound; TLP is the one
// axis not yet varied (m114: implicit wave-overlap is what delivers).
// LDS 32KB (2buf A+B).  Swizzle identical (row offsets all ==0 mod 8).
__global__ __launch_bounds__(256, 4) void gemm64(const u16* __restrict__ A, const u16* __restrict__ Bt,
    u16* __restrict__ C, float* __restrict__ Cf, int M, int N, int K,
    const float* __restrict__ bias, const u16* __restrict__ residual, int do_relu, int gx)
{
  __shared__ __align__(16) u16 As[2][64*64];
  __shared__ __align__(16) u16 Bs[2][64*64];
  int t = threadIdx.x;
  int bid = blockIdx.y * gridDim.x + blockIdx.x;
  int xcd = bid & 7, slot = bid >> 3;
  int gy = 8 / gx;
  int rx = gridDim.x / gx, ry = gridDim.y / gy;
  int col_b = (xcd % gx) * rx + (slot % rx);
  int row_b = (xcd / gx) * ry + (slot / rx);
  int row0 = row_b*64, col0 = col_b*64;
  int l = t&63, w = t>>6;
  int lr = l&15, lq = l>>4;
  (void)M;

  f32x4 acc[4];
  #pragma unroll
  for (int j=0;j<4;++j) acc[j] = f32x4{0.f,0.f,0.f,0.f};

  const u16* gA = A  + (size_t)(row0 + (t>>3))*K + (((t&7)^((t>>3)&7))<<3);
  const u16* gB = Bt + (size_t)(col0 + (t>>3))*K + (((t&7)^((t>>3)&7))<<3);
  const size_t rnd = (size_t)32*K;
  int nk = K>>6;

  #pragma unroll
  for (int r=0;r<2;++r){
    async16(gA + r*rnd, As[0] + r*2048 + t*8);
    async16(gB + r*rnd, Bs[0] + r*2048 + t*8);
  }

  int sw8 = (lr&7);
  for (int kt=0; kt<nk; ++kt){
    int cur = kt&1;
    __syncthreads();
    if (kt+1 < nk){
      int ko = (kt+1)<<6;
      #pragma unroll
      for (int r=0;r<2;++r){
        async16(gA + r*rnd + ko, As[cur^1] + r*2048 + t*8);
        async16(gB + r*rnd + ko, Bs[cur^1] + r*2048 + t*8);
      }
    }
    const u16* as = As[cur];
    const u16* bs = Bs[cur];
    #pragma unroll
    for (int kk=0;kk<2;++kk){
      int so = (((kk*4+lq)^sw8))<<3;
      short8 a = *(const short8*)(as + (w*16+lr)*64 + so);
      short8 b[4];
      #pragma unroll
      for (int j=0;j<4;++j) b[j] = *(const short8*)(bs + (j*16+lr)*64 + so);
      #pragma unroll
      for (int j=0;j<4;++j)
        acc[j] = __builtin_amdgcn_mfma_f32_16x16x32_bf16(a, b[j], acc[j], 0,0,0);
    }
  }

  #pragma unroll
  for (int j=0;j<4;++j){
    int col = col0 + j*16 + lr;
    float bv = bias ? bias[col] : 0.0f;
    #pragma unroll
    for (int r=0;r<4;++r){
      int row = row0 + w*16 + lq*4 + r;
      float v = acc[j][r] + bv;
      if (do_relu) v = fmaxf(v, 0.0f);
      if (residual) v += b2f(residual[(size_t)row*N + col]);
      if (Cf) Cf[(size_t)row*N + col] = v;
      else    C [(size_t)row*N + col] = f2b(v);
    }
  }
}

// ---------------- bf16 GEMM 256x256 tile, 8 waves, 4-phase/K-tile ----------------
// v5: 1 half-tile staged per phase; vmcnt(8) only at p_b/p_d; no manual lgkmcnt
// pins (compiler schedules ds_read->MFMA).  Counted vmcnt asm fences LDS reads
// against async global_load_lds writes; raw s_barrier orders cross-wave.
__global__ __launch_bounds__(512,2) void gemm256(const u16* __restrict__ A, const u16* __restrict__ Bt,
    u16* __restrict__ C, float* __restrict__ Cf, int N, int K,
    const float* __restrict__ bias, const u16* __restrict__ residual, int do_relu, int gx)
{
  __shared__ __align__(16) u16 As[2][256*64];
  __shared__ __align__(16) u16 Bs[2][256*64];
  int t = threadIdx.x;
  int bid = blockIdx.y*gridDim.x + blockIdx.x;
  int xcd = bid & 7, slot = bid >> 3;
  int gy = 8/gx;
  int rx = gridDim.x/gx, ry = gridDim.y/gy;
  int col_b = (xcd%gx)*rx + slot%rx;
  int row_b = (xcd/gx)*ry + slot/rx;
  int row0 = row_b*256, col0 = col_b*256;
  int l = t&63, w = t>>6;
  int wr = w>>2, wc = w&3;           // 2 x 4 wave grid, per-wave 128(M) x 64(N)
  int lr = l&15, lq = l>>4, sw = lr&7;

  f32x4 acc[8][4];
  #pragma unroll
  for (int m=0;m<8;++m)
    #pragma unroll
    for (int n=0;n<4;++n) acc[m][n] = f32x4{0.f,0.f,0.f,0.f};

  int i = t>>3, c8 = t&7;
  int swc = (c8 ^ (i&7))*8;
  const u16* aS[4]; const u16* bS[4];
  {
    int la[4] = { i, 128+i, 64+i, 192+i };
    #pragma unroll
    for (int s=0;s<4;++s){
      aS[s] = A + (size_t)(row0 + la[s])*K + swc;
      int p = s*64 + i;
      int lb = ((p>>5)&3)*64 + (p>>7)*32 + (p&31);
      bS[s] = Bt + (size_t)(col0 + lb)*K + swc;
    }
  }
  int nk = K>>6;   // requires nk >= 3

  u16* A0p = As[0]; u16* A1p = As[1];
  u16* B0p = Bs[0]; u16* B1p = Bs[1];

  short8 af[4][2], bP[2][2], bQ[2][2];

#define VM8  asm volatile("s_waitcnt vmcnt(8)" ::: "memory");
#define VM6  asm volatile("s_waitcnt vmcnt(6)" ::: "memory");
#define VM0  asm volatile("s_waitcnt vmcnt(0)" ::: "memory");
#define BAR  __builtin_amdgcn_s_barrier();

#define RD_A(BUF,qm) \
  _Pragma("unroll") \
  for (int mm=0;mm<4;++mm){ \
    _Pragma("unroll") \
    for (int kk=0;kk<2;++kk) \
      af[mm][kk] = *(const short8*)((const u16*)(BUF) + ((qm)*128 + wr*64 + mm*16 + lr)*64 + (((kk*4+lq)^sw)<<3)); \
  }
#define RD_B(DST,BUF,qn) \
  _Pragma("unroll") \
  for (int nn=0;nn<2;++nn){ \
    _Pragma("unroll") \
    for (int kk=0;kk<2;++kk) \
      DST[nn][kk] = *(const short8*)((const u16*)(BUF) + ((qn)*128 + wc*32 + nn*16 + lr)*64 + (((kk*4+lq)^sw)<<3)); \
  }
#define MMQ(qm,qn,BSS) \
  __builtin_amdgcn_s_setprio(1); \
  _Pragma("unroll") \
  for (int mm=0;mm<4;++mm){ \
    _Pragma("unroll") \
    for (int nn=0;nn<2;++nn){ \
      _Pragma("unroll") \
      for (int kk=0;kk<2;++kk) \
        acc[(qm)*4+mm][(qn)*2+nn] = __builtin_amdgcn_mfma_f32_16x16x32_bf16(af[mm][kk], BSS[nn][kk], acc[(qm)*4+mm][(qn)*2+nn], 0,0,0); \
    } \
  } \
  __builtin_amdgcn_s_setprio(0);

  // prologue: 14 loads — tile0 {A0,B0,B1,A1} -> buf0; tile1 {A0,B0,B1} -> buf1
  async16(aS[0], A0p + 0*4096 + t*8);
  async16(aS[1], A0p + 1*4096 + t*8);
  async16(bS[0], B0p + 0*4096 + t*8);
  async16(bS[1], B0p + 1*4096 + t*8);
  async16(bS[2], B0p + 2*4096 + t*8);
  async16(bS[3], B0p + 3*4096 + t*8);
  async16(aS[2], A0p + 2*4096 + t*8);
  async16(aS[3], A0p + 3*4096 + t*8);
  async16(aS[0]+64, A1p + 0*4096 + t*8);
  async16(aS[1]+64, A1p + 1*4096 + t*8);
  async16(bS[0]+64, B1p + 0*4096 + t*8);
  async16(bS[1]+64, B1p + 1*4096 + t*8);
  async16(bS[2]+64, B1p + 2*4096 + t*8);
  async16(bS[3]+64, B1p + 3*4096 + t*8);
  VM8; BAR;                               // retires tile0 {A0,B0,B1}
  RD_A(A0p, 0); RD_B(bP, B0p, 0);

  for (int kt=0; kt<nk-1; ++kt){
    int cur = kt&1;
    u16* Ac = As[cur]; u16* Bc = Bs[cur];
    u16* An = As[cur^1]; u16* Bn = Bs[cur^1];
    int ko1 = (kt+1)<<6;
    int kc2 = (kt+2 < nk) ? kt+2 : nk-1;
    int ko2 = kc2<<6;
    // p_a: MMQ(0,0); stage A1(k+1)->next buf
    async16(aS[2]+ko1, An + 2*4096 + t*8);
    async16(aS[3]+ko1, An + 3*4096 + t*8);
    BAR;
    MMQ(0,0,bP);
    RD_B(bQ, Bc, 1);
    BAR;
    // p_b: MMQ(0,1); stage B1(k+2)->cur buf; wait
    async16(bS[2]+ko2, Bc + 2*4096 + t*8);
    async16(bS[3]+ko2, Bc + 3*4096 + t*8);
    VM8; BAR;
    MMQ(0,1,bQ);
    RD_A(Ac, 1);
    BAR;
    // p_c: MMQ(1,1); stage A0(k+2)->cur buf
    async16(aS[0]+ko2, Ac + 0*4096 + t*8);
    async16(aS[1]+ko2, Ac + 1*4096 + t*8);
    BAR;
    MMQ(1,1,bQ);
    BAR;
    // p_d: MMQ(1,0); stage B0(k+2)->cur buf; wait; prefetch-read next A0,B0
    async16(bS[0]+ko2, Bc + 0*4096 + t*8);
    async16(bS[1]+ko2, Bc + 1*4096 + t*8);
    VM8; BAR;
    MMQ(1,0,bP);
    RD_A(An, 0); RD_B(bP, Bn, 0);
    BAR;
  }
  { // tail tile (nk-1): no staging
    int cur = (nk-1)&1;
    u16* Ac = As[cur]; u16* Bc = Bs[cur];
    BAR;
    MMQ(0,0,bP);
    RD_B(bQ, Bc, 1);
    BAR;
    VM6; BAR;                             // retires A1(nk-1)
    MMQ(0,1,bQ);
    RD_A(Ac, 1);
    MMQ(1,1,bQ);
    MMQ(1,0,bP);
  }
  VM0;   // drain remaining async LDS writes before epilogue

#undef VM8
#undef VM6
#undef VM0
#undef BAR
#undef RD_A
#undef RD_B
#undef MMQ

  #pragma unroll
  for (int m=0;m<8;++m){
    #pragma unroll
    for (int n=0;n<4;++n){
      int col = col0 + wc*64 + n*16 + lr;
      float bv = bias ? bias[col] : 0.0f;
      #pragma unroll
      for (int r=0;r<4;++r){
        int row = row0 + wr*128 + m*16 + lq*4 + r;
        float v = acc[m][n][r] + bv;
        if (do_relu) v = fmaxf(v, 0.0f);
        if (residual) v += b2f(residual[(size_t)row*N + col]);
        if (Cf) Cf[(size_t)row*N + col] = v;
        else    C [(size_t)row*N + col] = f2b(v);
      }
    }
  }
}

// ---------------- causal flash attention v4 ----------------
// Q-tile 64 (4 waves x 16 q rows), s-tile 64 double-buffered, grid 1024.
// S^T via K=32 mfma; P stays IN-LANE (C-layout == K=16 A-layout), PV via
// 16x16x16 mfma on packed bf16 — no P LDS round-trip. Complementary-qt
// slot pairing balances per-CU work. K and V^T staged via global_load_lds.
__global__ __launch_bounds__(256,4) void attn_kernel(const u16* __restrict__ QKV,
    const u16* __restrict__ VT, u16* __restrict__ O)
{
  const int T=2048, LD=3072, E=1024;
  int bid = blockIdx.y * gridDim.x + blockIdx.x;
  int xcd = bid & 7, slot = bid >> 3;
  int idx = slot & 31, grp = slot >> 5;
  int qt = (grp & 1) ? idx : 31 - idx;   // heavy-first, complementary pairing
  int bh = xcd*4 + grp;
  int bb = bh>>4, h = bh&15;
  const u16* base = QKV + (size_t)bb*T*LD;
  const u16* Qp = base + h*64;
  const u16* Kp = base + 1024 + h*64;
  const u16* Vtp = VT + (size_t)bh*64*2048;
  int t = threadIdx.x, l = t&63, w = t>>6;
  int lr = l&15, lq = l>>4;

  __shared__ __align__(16) u16 Ks[2][64*64];   // [s][d], chunk c at slot c^(s&7)
  __shared__ __align__(16) u16 Vs[2][64*64];   // [d][s], chunk c at slot c^(d&7)

  const float QSC = 0.125f*1.44269504f;
  int q0 = qt*64 + w*16;
  short8 aq[2];
  #pragma unroll
  for (int kk=0;kk<2;++kk){
    short8 raw = *(const short8*)(Qp + (size_t)(q0+lr)*LD + kk*32 + lq*8);
    short8 sc;
    #pragma unroll
    for (int j=0;j<8;++j) sc[j] = (short)f2b(b2f((u16)raw[j])*QSC);
    aq[kk]=sc;
  }

  float mrun = -3e38f, lrun = 0.f;
  f32x4 Oacc[4];
  #pragma unroll
  for (int dt=0;dt<4;++dt) Oacc[dt] = f32x4{0.f,0.f,0.f,0.f};

  int kc = (l&7) ^ (l>>3);
  int ra = 8*w + (l>>3);

  // prologue: stage tile 0
  async16(Kp  + (size_t)ra*LD        + kc*8, Ks[0] + t*8);
  async16(Kp  + (size_t)(ra+32)*LD   + kc*8, Ks[0] + 2048 + t*8);
  async16(Vtp + (size_t)ra*2048      + kc*8, Vs[0] + t*8);
  async16(Vtp + (size_t)(ra+32)*2048 + kc*8, Vs[0] + 2048 + t*8);

  for (int it=0; it<=qt; ++it){
    int s0 = it*64, cur = it&1;
    __syncthreads();
    if (it < qt){
      int sn = s0+64;
      u16* kd = Ks[cur^1]; u16* vd = Vs[cur^1];
      async16(Kp  + (size_t)(sn+ra)*LD        + kc*8, kd + t*8);
      async16(Kp  + (size_t)(sn+ra+32)*LD     + kc*8, kd + 2048 + t*8);
      async16(Vtp + (size_t)ra*2048      + sn + kc*8, vd + t*8);
      async16(Vtp + (size_t)(ra+32)*2048 + sn + kc*8, vd + 2048 + t*8);
    }
    const u16* ks = Ks[cur];
    const u16* vs = Vs[cur];

    // S^T[s][q] for this wave's 16 q
    f32x4 S[4];
    #pragma unroll
    for (int st=0; st<4; ++st){
      short8 kf0 = *(const short8*)(ks + (st*16+lr)*64 + ((lq  )^(lr&7))*8);
      short8 kf1 = *(const short8*)(ks + (st*16+lr)*64 + ((4+lq)^(lr&7))*8);
      f32x4 z = f32x4{0.f,0.f,0.f,0.f};
      z = __builtin_amdgcn_mfma_f32_16x16x32_bf16(kf0, aq[0], z, 0,0,0);
      z = __builtin_amdgcn_mfma_f32_16x16x32_bf16(kf1, aq[1], z, 0,0,0);
      S[st] = z;
    }
    if (it == qt){
      int qg = q0 + lr;
      #pragma unroll
      for (int st=0;st<4;++st)
        #pragma unroll
        for (int r=0;r<4;++r){
          int sg = s0 + st*16 + lq*4 + r;
          if (sg > qg) S[st][r] = -3e38f;
        }
    }
    // online softmax (q = lr; s-reduction in-lane + 2 shuffles)
    float m = S[0][0];
    #pragma unroll
    for (int st=0;st<4;++st)
      #pragma unroll
      for (int r=0;r<4;++r) m = fmaxf(m, S[st][r]);
    m = fmaxf(m, __shfl_xor(m,16));
    m = fmaxf(m, __shfl_xor(m,32));
    float mnew = fmaxf(mrun, m);
    float alpha = EXP2F(mrun - mnew);
    mrun = mnew;
    float ssum = 0.f;
    #pragma unroll
    for (int st=0;st<4;++st)
      #pragma unroll
      for (int r=0;r<4;++r){ float p = EXP2F(S[st][r]-mnew); S[st][r]=p; ssum+=p; }
    ssum += __shfl_xor(ssum,16);
    ssum += __shfl_xor(ssum,32);
    lrun = lrun*alpha + ssum;
    // P: in-lane pack to K=16 A-fragments
    short4_t pk[4];
    #pragma unroll
    for (int st=0;st<4;++st) pk[st] = pack4(S[st]);
    // rescale O (O rows: q = lq*4+r)
    float af[4];
    #pragma unroll
    for (int r=0;r<4;++r) af[r] = __shfl(alpha, lq*4+r);
    #pragma unroll
    for (int dt=0;dt<4;++dt)
      #pragma unroll
      for (int r=0;r<4;++r) Oacc[dt][r] *= af[r];
    // PV: 16 x mfma_16x16x16
    #pragma unroll
    for (int st=0;st<4;++st){
      #pragma unroll
      for (int dt=0;dt<4;++dt){
        short4_t vf = *(const short4_t*)(vs + (dt*16+lr)*64 + ((2*st+(lq>>1))^(lr&7))*8 + (lq&1)*4);
        Oacc[dt] = MFMA16(pk[st], vf, Oacc[dt]);
      }
    }
  }
  float linv[4];
  #pragma unroll
  for (int r=0;r<4;++r) linv[r] = 1.0f/__shfl(lrun, lq*4+r);
  #pragma unroll
  for (int dt=0;dt<4;++dt)
    #pragma unroll
    for (int r=0;r<4;++r){
      int qg = q0 + lq*4 + r;
      O[(size_t)(bb*T+qg)*E + h*64 + dt*16 + lr] = f2b(Oacc[dt][r]*linv[r]);
    }
}

// ---------------- host ----------------
extern "C" void kernel_launch(void* const* d_in, const int* in_sizes, int n_in,
                              void* d_out, int out_size, void* d_ws, size_t ws_size,
                              hipStream_t stream)
{
  (void)in_sizes; (void)n_in; (void)out_size; (void)ws_size;
  const float* x     = (const float*)d_in[0];
  const float* wq    = (const float*)d_in[1];
  const float* wk    = (const float*)d_in[2];
  const float* wv    = (const float*)d_in[3];
  const float* wproj = (const float*)d_in[4];
  const float* bproj = (const float*)d_in[5];
  const float* g1    = (const float*)d_in[6];
  const float* be1   = (const float*)d_in[7];
  const float* g2    = (const float*)d_in[8];
  const float* be2   = (const float*)d_in[9];
  const float* w1    = (const float*)d_in[10];
  const float* b1    = (const float*)d_in[11];
  const float* w2    = (const float*)d_in[12];
  const float* b2    = (const float*)d_in[13];
  float* out = (float*)d_out;

  char* ws = (char*)d_ws;
  size_t off = 0;
  auto alloc = [&](size_t bytes)->void*{ void* p = ws + off; off += (bytes + 255) & ~(size_t)255; return p; };
  u16* hnorm  = (u16*)alloc((size_t)4096*1024*2);
  u16* qkv    = (u16*)alloc((size_t)4096*3072*2);
  u16* VT     = (u16*)alloc((size_t)32*64*2048*2);
  u16* attnO  = (u16*)alloc((size_t)4096*1024*2);
  u16* x2     = (u16*)alloc((size_t)4096*1024*2);
  u16* h2     = (u16*)alloc((size_t)4096*1024*2);
  u16* ffn1   = (u16*)alloc((size_t)4096*4096*2);
  u16* wqkvT  = (u16*)alloc((size_t)3072*1024*2);
  u16* wprojT = (u16*)alloc((size_t)1024*1024*2);
  u16* w1T    = (u16*)alloc((size_t)4096*1024*2);
  u16* w2T    = (u16*)alloc((size_t)1024*4096*2);

  qkv_repack  <<<dim3(16,48),256,0,stream>>>(wq,wk,wv,wqkvT);
  transpose_bt<<<dim3(16,16),256,0,stream>>>(wproj, wprojT, 1024, 1024);
  transpose_bt<<<dim3(64,16),256,0,stream>>>(w1,    w1T,    4096, 1024);
  transpose_bt<<<dim3(16,64),256,0,stream>>>(w2,    w2T,    1024, 4096);

  ln_kernel<1><<<4096,256,0,stream>>>(x, g1, be1, hnorm);
  gemm256<<<dim3(12,16),512,0,stream>>>(hnorm, wqkvT, qkv, nullptr, 3072, 1024, nullptr, nullptr, 0, 4);
  vtrans<<<dim3(32,32),256,0,stream>>>(qkv, VT);
  attn_kernel<<<dim3(32,32),256,0,stream>>>(qkv, VT, attnO);
  gemm64<<<dim3(16,64),256,0,stream>>>(attnO, wprojT, x2, nullptr, 4096,1024,1024, bproj, hnorm, 0, 4);
  ln_kernel<0><<<4096,256,0,stream>>>(x2, g2, be2, h2);
  gemm256<<<dim3(16,16),512,0,stream>>>(h2, w1T, ffn1, nullptr, 4096, 1024, b1, nullptr, 1, 4);
  gemm64<<<dim3(16,64),256,0,stream>>>(ffn1, w2T, nullptr, out, 4096,1024,4096, b2, h2, 0, 4);
}